// Round 13
// baseline (226.581 us; speedup 1.0000x reference)
//
#include <hip/hip_runtime.h>
#include <math.h>

#define KSIZE 5
#define KTOT 125
#define CHUNK 2048

static constexpr float LOWER_CURV = -0.22703196f;
static constexpr float UPPER_CURV = 0.36853024f;

typedef _Float16 h2 __attribute__((ext_vector_type(2)));

__device__ __forceinline__ unsigned pack_u32(float a, float b) {
    return __builtin_bit_cast(unsigned, __builtin_amdgcn_cvt_pkrtz(a, b));
}
__device__ __forceinline__ float fdot2f(h2 a, h2 b, float c) {
#if __has_builtin(__builtin_amdgcn_fdot2)
    return __builtin_amdgcn_fdot2(a, b, c, false);
#else
    return c + (float)a[0] * (float)b[0] + (float)a[1] * (float)b[1];
#endif
}

__host__ __device__ static inline int cdiv(int a, int b) { return (a + b - 1) / b; }

// basis from 10-bit quantized fractions; bb[t] matches TAP[t]
__device__ __forceinline__ void unpack_bb10(unsigned w1, float bb[8]) {
    const float s = 1.0f / 1023.0f;
    float f0 = (float)(w1 & 1023u) * s;
    float f1 = (float)((w1 >> 10) & 1023u) * s;
    float f2 = (float)((w1 >> 20) & 1023u) * s;
    float a0 = 1.f - f0, a1 = 1.f - f1, a2 = 1.f - f2;
    float p00 = a0 * a1, p10 = f0 * a1, p01 = a0 * f1, p11 = f0 * f1;
    bb[0] = p00 * a2; bb[1] = p10 * a2; bb[2] = p01 * a2; bb[3] = p11 * a2;
    bb[4] = p00 * f2; bb[5] = p10 * f2; bb[6] = p01 * f2; bb[7] = p11 * f2;
}

__device__ __forceinline__ void spline_wf(const float* __restrict__ a3,
                                          int& wib, float fr[3]) {
    int k[3];
#pragma unroll
    for (int d = 0; d < 3; ++d) {
        float p = fminf(fmaxf(a3[d], 0.f), 1.f) * 4.f;
        float f0 = fminf(floorf(p), 3.f);
        k[d] = (int)f0;
        fr[d] = p - f0;
    }
    wib = k[0] * 25 + k[1] * 5 + k[2];
}

// ---------- preamble kernels ----------

// dst histogram (counts pre-zeroed by memset) + x transform, one launch
__global__ void hist_tr(const float* __restrict__ x, float* __restrict__ h,
                        const int* __restrict__ dst, int* __restrict__ counts,
                        int N, int E) {
    int i = blockIdx.x * blockDim.x + threadIdx.x;
    if (i < E) atomicAdd(&counts[dst[i]], 1);
    if (i < N) {
        float t = (x[i] - LOWER_CURV) / (UPPER_CURV - LOWER_CURV) * 20.0f - 10.0f;
        h[i] = fminf(fmaxf(t, -10.0f), 10.0f);
    }
}

__global__ void scan_blocks(const int* __restrict__ counts, int* __restrict__ rowptr,
                            int* __restrict__ bsums, int n) {
    __shared__ int sh[256];
    int tid = threadIdx.x;
    int i = blockIdx.x * 256 + tid;
    int v = (i < n) ? counts[i] : 0;
    sh[tid] = v;
    __syncthreads();
    for (int off = 1; off < 256; off <<= 1) {
        int t = (tid >= off) ? sh[tid - off] : 0;
        __syncthreads();
        sh[tid] += t;
        __syncthreads();
    }
    if (i < n) rowptr[i] = sh[tid] - v;
    if (tid == 255) bsums[blockIdx.x] = sh[255];
}

// per-block redundant scan of bsums, then offset rowptr & init cursor (1 launch)
__global__ void add_offsets2(int* __restrict__ rowptr, const int* __restrict__ bsums,
                             int* __restrict__ cursor, int nb, int n, int E) {
    __shared__ int sh[256];
    int tid = threadIdx.x;
    int v = (tid < nb) ? bsums[tid] : 0;
    sh[tid] = v;
    __syncthreads();
    for (int off = 1; off < 256; off <<= 1) {
        int t = (tid >= off) ? sh[tid - off] : 0;
        __syncthreads();
        sh[tid] += t;
        __syncthreads();
    }
    int boff = (blockIdx.x == 0) ? 0 : sh[blockIdx.x - 1];
    int i = blockIdx.x * 256 + tid;
    if (i < n) {
        int r = rowptr[i] + boff;
        rowptr[i] = r;
        cursor[i] = r;
    }
    if (i == 0) rowptr[n] = E;
}

// chunk-local counting sort by wib (blocks < nchunk) + f16 weight-table prep
// (tail blocks). Records are 8B: w0 = src | wib<<18; w1 = q0|q1<<10|q2<<20.
__global__ __launch_bounds__(256) void scatter_prep(
        const int* __restrict__ src, const int* __restrict__ dst,
        const float* __restrict__ attr, int* __restrict__ cursor,
        uint2* __restrict__ records, uint2* __restrict__ records_d,
        int* __restrict__ iperm, int E, int nchunk,
        const float* __restrict__ W2, const float* __restrict__ W3,
        const float* __restrict__ W4, _Float16* __restrict__ wh2,
        _Float16* __restrict__ wh3, _Float16* __restrict__ wh4) {
    __shared__ int lh[KTOT], lbase[KTOT], lrank[KTOT];
    __shared__ int sb[128];
    const int tid = threadIdx.x;

    if ((int)blockIdx.x >= nchunk) {
        // ---- weight prep path: Wh[wi][(i>>3)][o][i&7] = W[wi][i][o] ----
        int idx = ((int)blockIdx.x - nchunk) * 256 + tid;   // < 64000
        const float* W; _Float16* Wh; int Cin, Cout, r;
        if (idx < 16000)      { W = W2; Wh = wh2; Cin = 8;  Cout = 16; r = idx; }
        else if (idx < 48000) { W = W3; Wh = wh3; Cin = 16; Cout = 16; r = idx - 16000; }
        else                  { W = W4; Wh = wh4; Cin = 16; Cout = 8;  r = idx - 48000; }
        int wi = r / (Cin * Cout);
        int q = r % (Cin * Cout);
        int i = q / Cout, o = q % Cout;
        Wh[wi * (Cin * Cout) + (i >> 3) * (8 * Cout) + o * 8 + (i & 7)] = (_Float16)W[r];
        return;
    }

    for (int i = tid; i < KTOT; i += 256) { lh[i] = 0; lrank[i] = 0; }
    __syncthreads();
    const int base = blockIdx.x * CHUNK;

    int wibs[8]; unsigned w1s[8];
#pragma unroll
    for (int k = 0; k < 8; ++k) {
        int e = base + tid + k * 256;
        wibs[k] = -1;
        if (e < E) {
            float a3[3] = {attr[e * 3], attr[e * 3 + 1], attr[e * 3 + 2]};
            int wib; float fr[3];
            spline_wf(a3, wib, fr);
            wibs[k] = wib;
            unsigned q0 = (unsigned)__float2int_rn(fr[0] * 1023.f);
            unsigned q1 = (unsigned)__float2int_rn(fr[1] * 1023.f);
            unsigned q2 = (unsigned)__float2int_rn(fr[2] * 1023.f);
            w1s[k] = q0 | (q1 << 10) | (q2 << 20);
            atomicAdd(&lh[wib], 1);
        }
    }
    __syncthreads();
    int v0 = 0;
    if (tid < 128) {
        v0 = (tid < KTOT) ? lh[tid] : 0;
        sb[tid] = v0;
    }
    __syncthreads();
    for (int off = 1; off < 128; off <<= 1) {
        int t = (tid >= off && tid < 128) ? sb[tid - off] : 0;
        __syncthreads();
        if (tid < 128) sb[tid] += t;
        __syncthreads();
    }
    if (tid < KTOT) lbase[tid] = sb[tid] - v0;
    __syncthreads();
#pragma unroll
    for (int k = 0; k < 8; ++k) {
        int e = base + tid + k * 256;
        if (e < E) {
            int w = wibs[k];
            int pos = base + lbase[w] + atomicAdd(&lrank[w], 1);
            uint2 rec = make_uint2((unsigned)src[e] | ((unsigned)w << 18), w1s[k]);
            records[pos] = rec;
            int p = atomicAdd(&cursor[dst[e]], 1);
            iperm[pos] = p;
            records_d[p] = rec;
        }
    }
}

// ---------- phase A: edge GEMM; LDS weights, 2-way window unroll for MLP ----------
template<int Cin, int Cout>
__global__ __launch_bounds__(512) void edge_gemm(
        const uint2* __restrict__ records, const unsigned* __restrict__ xh,
        const _Float16* __restrict__ Wg, const int* __restrict__ iperm,
        _Float16* __restrict__ y, int E) {
    constexpr int SLOTS = 64 / Cout;
    constexpr int CC = Cin * Cout;
    constexpr int WH = KTOT * CC;
    __shared__ __align__(16) _Float16 Wl[WH];
    for (int t = threadIdx.x; t < WH / 8; t += 512)
        ((uint4*)Wl)[t] = ((const uint4*)Wg)[t];
    __syncthreads();

    const int lane = threadIdx.x & 63;
    const int o = lane & (Cout - 1);
    const int slot = lane / Cout;
    const int wid = blockIdx.x * 8 + (threadIdx.x >> 6);
    const int stride = gridDim.x * 8;
    constexpr int TAP[8] = {0, 25, 5, 30, 1, 26, 6, 31};

    for (int base = wid * 2 * SLOTS; base < E; base += stride * 2 * SLOTS) {
        const int idxA = base + slot;
        const int idxB = base + SLOTS + slot;
        const bool actA = idxA < E;
        const bool actB = idxB < E;
        // both record + iperm loads issued up front
        uint2 recA = actA ? records[idxA] : make_uint2(0u, 0u);
        uint2 recB = actB ? records[idxB] : make_uint2(0u, 0u);
        int dposA = actA ? iperm[idxA] : 0;
        int dposB = actB ? iperm[idxB] : 0;

        const unsigned snA = recA.x & 0x3FFFFu;
        const unsigned snB = recB.x & 0x3FFFFu;
        const int wibA = (int)(recA.x >> 18);
        const int wibB = (int)(recB.x >> 18);

        // both x-gathers issued before any compute
        h2 hxA[Cin / 2], hxB[Cin / 2];
        const uint4* xpA = (const uint4*)(xh + (size_t)snA * (Cin / 2));
        const uint4* xpB = (const uint4*)(xh + (size_t)snB * (Cin / 2));
#pragma unroll
        for (int c = 0; c < Cin / 8; ++c) {
            uint4 qA = xpA[c];
            uint4 qB = xpB[c];
            hxA[4 * c + 0] = __builtin_bit_cast(h2, qA.x);
            hxA[4 * c + 1] = __builtin_bit_cast(h2, qA.y);
            hxA[4 * c + 2] = __builtin_bit_cast(h2, qA.z);
            hxA[4 * c + 3] = __builtin_bit_cast(h2, qA.w);
            hxB[4 * c + 0] = __builtin_bit_cast(h2, qB.x);
            hxB[4 * c + 1] = __builtin_bit_cast(h2, qB.y);
            hxB[4 * c + 2] = __builtin_bit_cast(h2, qB.z);
            hxB[4 * c + 3] = __builtin_bit_cast(h2, qB.w);
        }
        float bbA[8], bbB[8];
        unpack_bb10(recA.y, bbA);
        unpack_bb10(recB.y, bbB);

        float accA = 0.f, accB = 0.f;
#pragma unroll
        for (int t = 0; t < 8; ++t) {
            const _Float16* wpA = &Wl[(wibA + TAP[t]) * CC + o * 8];
            const _Float16* wpB = &Wl[(wibB + TAP[t]) * CC + o * 8];
            float dotA = 0.f, dotB = 0.f;
#pragma unroll
            for (int c = 0; c < Cin / 8; ++c) {
                union { uint4 u4; unsigned u[4]; } wuA, wuB;
                wuA.u4 = *(const uint4*)(wpA + c * (8 * Cout));
                wuB.u4 = *(const uint4*)(wpB + c * (8 * Cout));
                dotA = fdot2f(hxA[4 * c + 0], __builtin_bit_cast(h2, wuA.u[0]), dotA);
                dotA = fdot2f(hxA[4 * c + 1], __builtin_bit_cast(h2, wuA.u[1]), dotA);
                dotA = fdot2f(hxA[4 * c + 2], __builtin_bit_cast(h2, wuA.u[2]), dotA);
                dotA = fdot2f(hxA[4 * c + 3], __builtin_bit_cast(h2, wuA.u[3]), dotA);
                dotB = fdot2f(hxB[4 * c + 0], __builtin_bit_cast(h2, wuB.u[0]), dotB);
                dotB = fdot2f(hxB[4 * c + 1], __builtin_bit_cast(h2, wuB.u[1]), dotB);
                dotB = fdot2f(hxB[4 * c + 2], __builtin_bit_cast(h2, wuB.u[2]), dotB);
                dotB = fdot2f(hxB[4 * c + 3], __builtin_bit_cast(h2, wuB.u[3]), dotB);
            }
            accA = fmaf(bbA[t], dotA, accA);
            accB = fmaf(bbB[t], dotB, accB);
        }
        if (actA) y[(size_t)dposA * Cout + o] = (_Float16)accA;
        if (actB) y[(size_t)dposB * Cout + o] = (_Float16)accB;
    }
}

// ---------- phase B: sequential y reduce + root + ELU; writes f32 + packed f16 ----------
template<int Cin, int Cout>
__global__ void node_reduce(const int* __restrict__ rowptr,
                            const unsigned* __restrict__ yu,
                            const float* __restrict__ x,
                            const float* __restrict__ root,
                            const float* __restrict__ bias,
                            float* __restrict__ out, unsigned* __restrict__ xh,
                            int N) {
    constexpr int C2 = Cout / 2;
    int t = blockIdx.x * blockDim.x + threadIdx.x;
    int v = t / C2, o2 = t % C2;
    if (v >= N) return;
    int beg = rowptr[v], end = rowptr[v + 1];
    float a0 = 0.f, a1 = 0.f;
    for (int p = beg; p < end; ++p) {
        h2 hh = __builtin_bit_cast(h2, yu[(size_t)p * C2 + o2]);
        a0 += (float)hh[0];
        a1 += (float)hh[1];
    }
    const int o = 2 * o2;
    a0 += bias[o]; a1 += bias[o + 1];
#pragma unroll
    for (int i = 0; i < Cin; ++i) {
        float xv = x[(size_t)v * Cin + i];
        a0 = fmaf(xv, root[i * Cout + o], a0);
        a1 = fmaf(xv, root[i * Cout + o + 1], a1);
    }
    a0 = a0 > 0.f ? a0 : expm1f(a0);
    a1 = a1 > 0.f ? a1 : expm1f(a1);
    ((float2*)out)[(size_t)v * C2 + o2] = make_float2(a0, a1);
    xh[(size_t)v * C2 + o2] = pack_u32(a0, a1);
}

// ---------- fused small layers (records_d in dst-CSR order: contiguous reads) ----------

__global__ __launch_bounds__(512) void agg_l1(
        const int* __restrict__ rowptr, const uint2* __restrict__ records_d,
        const float* __restrict__ x, const float* __restrict__ W,
        const float* __restrict__ root, const float* __restrict__ bias,
        float* __restrict__ out, unsigned* __restrict__ xh2,
        int N, int totalWaves) {
    const int lane = threadIdx.x & 63;
    const int o = lane & 7;
    const int slot = lane >> 3;
    const int wid = blockIdx.x * 8 + (threadIdx.x >> 6);
    constexpr int TAP[8] = {0, 25, 5, 30, 1, 26, 6, 31};

    for (int v = wid; v < N; v += totalWaves) {
        const int beg = rowptr[v], end = rowptr[v + 1];
        float acc = 0.0f;
        for (int p0 = beg; p0 < end; p0 += 8) {
            const int p = p0 + slot;
            float xv = 0.f, bb[8];
            int wib = 0;
#pragma unroll
            for (int t = 0; t < 8; ++t) bb[t] = 0.f;
            if (p < end) {
                uint2 rec = records_d[p];
                unpack_bb10(rec.y, bb);
                wib = (int)(rec.x >> 18);
                xv = x[rec.x & 0x3FFFFu];
            }
#pragma unroll
            for (int t = 0; t < 8; ++t)
                acc = fmaf(bb[t] * xv, __ldg(&W[(wib + TAP[t]) * 8 + o]), acc);
        }
#pragma unroll
        for (int m = 8; m < 64; m <<= 1) acc += __shfl_xor(acc, m);
        if (slot == 0) {
            float z = acc + bias[o] + x[v] * root[o];
            z = z > 0.0f ? z : expm1f(z);
            out[(size_t)v * 8 + o] = z;
            float zp = __shfl_xor(z, 1);
            if ((o & 1) == 0) xh2[(size_t)v * 4 + (o >> 1)] = pack_u32(z, zp);
        }
    }
}

__global__ __launch_bounds__(512) void agg_l5(
        const int* __restrict__ rowptr, const uint2* __restrict__ records_d,
        const float* __restrict__ x, const float* __restrict__ W,
        const float* __restrict__ root, const float* __restrict__ bias,
        float* __restrict__ out, int N, int totalWaves) {
    const int lane = threadIdx.x & 63;
    const int i = lane & 7;
    const int slot = lane >> 3;
    const int wid = blockIdx.x * 8 + (threadIdx.x >> 6);
    constexpr int TAP[8] = {0, 25, 5, 30, 1, 26, 6, 31};

    for (int v = wid; v < N; v += totalWaves) {
        const int beg = rowptr[v], end = rowptr[v + 1];
        float acc = 0.0f;
        for (int p0 = beg; p0 < end; p0 += 8) {
            const int p = p0 + slot;
            float xi = 0.f, bb[8];
            int wib = 0;
#pragma unroll
            for (int t = 0; t < 8; ++t) bb[t] = 0.f;
            if (p < end) {
                uint2 rec = records_d[p];
                unpack_bb10(rec.y, bb);
                wib = (int)(rec.x >> 18);
                xi = x[(size_t)(rec.x & 0x3FFFFu) * 8 + i];
            }
#pragma unroll
            for (int t = 0; t < 8; ++t)
                acc = fmaf(bb[t] * xi, __ldg(&W[(wib + TAP[t]) * 8 + i]), acc);
        }
        if (slot == 0) acc = fmaf(x[(size_t)v * 8 + i], root[i], acc);
#pragma unroll
        for (int m = 1; m < 64; m <<= 1) acc += __shfl_xor(acc, m);
        if (lane == 0) {
            float z = acc + bias[0];
            out[v] = z > 0.0f ? z : expm1f(z);
        }
    }
}

// ---------- host ----------

static inline char* align256(char* p) {
    return (char*)(((uintptr_t)p + 255) & ~(uintptr_t)255);
}

extern "C" void kernel_launch(void* const* d_in, const int* in_sizes, int n_in,
                              void* d_out, int out_size, void* d_ws, size_t ws_size,
                              hipStream_t stream) {
    const float* x    = (const float*)d_in[0];
    const int*   ei   = (const int*)d_in[1];
    const float* attr = (const float*)d_in[2];
    const float* w[5]    = {(const float*)d_in[3],  (const float*)d_in[6],
                            (const float*)d_in[9],  (const float*)d_in[12],
                            (const float*)d_in[15]};
    const float* root[5] = {(const float*)d_in[4],  (const float*)d_in[7],
                            (const float*)d_in[10], (const float*)d_in[13],
                            (const float*)d_in[16]};
    const float* bias[5] = {(const float*)d_in[5],  (const float*)d_in[8],
                            (const float*)d_in[11], (const float*)d_in[14],
                            (const float*)d_in[17]};

    const int N = in_sizes[0];
    const int E = in_sizes[1] / 2;
    const int* src = ei;
    const int* dst = ei + E;

    char* ws = (char*)d_ws;
    float* bufA      = (float*)ws;    ws = align256(ws + (size_t)N * 16 * 4);
    float* bufB      = (float*)ws;    ws = align256(ws + (size_t)N * 16 * 4);
    int*   counts    = (int*)ws;      ws = align256(ws + (size_t)N * 4);
    int*   cursor    = (int*)ws;      ws = align256(ws + (size_t)N * 4);
    int*   rowptr    = (int*)ws;      ws = align256(ws + (size_t)(N + 1) * 4);
    int*   bsums     = (int*)ws;      ws = align256(ws + 256 * 4);
    uint2* records   = (uint2*)ws;    ws = align256(ws + (size_t)E * 8);
    uint2* records_d = (uint2*)ws;    ws = align256(ws + (size_t)E * 8);
    int*   iperm     = (int*)ws;      ws = align256(ws + (size_t)E * 4);
    _Float16* y      = (_Float16*)ws; ws = align256(ws + (size_t)E * 16 * 2);
    unsigned* xhA    = (unsigned*)ws; ws = align256(ws + (size_t)N * 8 * 4);
    unsigned* xhB    = (unsigned*)ws; ws = align256(ws + (size_t)N * 8 * 4);
    _Float16* wh2    = (_Float16*)ws; ws = align256(ws + (size_t)KTOT * 8 * 16 * 2);
    _Float16* wh3    = (_Float16*)ws; ws = align256(ws + (size_t)KTOT * 16 * 16 * 2);
    _Float16* wh4    = (_Float16*)ws; ws = align256(ws + (size_t)KTOT * 16 * 8 * 2);

    const int B = 256;
    const int nb = cdiv(N, 256);
    const int nchunk = cdiv(E, CHUNK);
    const int nprep = cdiv(64000, 256);
    const unsigned* yu = (const unsigned*)y;

    (void)hipMemsetAsync(counts, 0, (size_t)N * 4, stream);
    hist_tr<<<cdiv(E, B), B, 0, stream>>>(x, bufA, dst, counts, N, E);
    scan_blocks<<<nb, 256, 0, stream>>>(counts, rowptr, bsums, N);
    add_offsets2<<<nb, 256, 0, stream>>>(rowptr, bsums, cursor, nb, N, E);
    scatter_prep<<<nchunk + nprep, 256, 0, stream>>>(
        src, dst, attr, cursor, records, records_d, iperm, E, nchunk,
        w[1], w[2], w[3], wh2, wh3, wh4);

    const int GB = 512, TW = GB * 8;

    // L1 (1->8), fused; writes f32 out + f16 xhA
    agg_l1<<<GB, 512, 0, stream>>>(rowptr, records_d, bufA, w[0],
                                   root[0], bias[0], bufB, xhA, N, TW);
    // L2 (8->16)
    edge_gemm<8, 16><<<1024, 512, 0, stream>>>(records, xhA, wh2, iperm, y, E);
    node_reduce<8, 16><<<cdiv(N * 8, B), B, 0, stream>>>(rowptr, yu, bufB,
                                                         root[1], bias[1], bufA, xhB, N);
    // L3 (16->16)
    edge_gemm<16, 16><<<512, 512, 0, stream>>>(records, xhB, wh3, iperm, y, E);
    node_reduce<16, 16><<<cdiv(N * 8, B), B, 0, stream>>>(rowptr, yu, bufA,
                                                          root[2], bias[2], bufB, xhA, N);
    // L4 (16->8)
    edge_gemm<16, 8><<<1024, 512, 0, stream>>>(records, xhA, wh4, iperm, y, E);
    node_reduce<16, 8><<<cdiv(N * 4, B), B, 0, stream>>>(rowptr, yu, bufB,
                                                         root[3], bias[3], bufA, xhB, N);
    // L5 (8->1), fused
    agg_l5<<<GB, 512, 0, stream>>>(rowptr, records_d, bufA, w[4],
                                   root[4], bias[4], (float*)d_out, N, TW);
}

// Round 14
// 204.546 us; speedup vs baseline: 1.1077x; 1.1077x over previous
//
#include <hip/hip_runtime.h>
#include <math.h>

#define KSIZE 5
#define KTOT 125
#define CHUNK 2048

static constexpr float LOWER_CURV = -0.22703196f;
static constexpr float UPPER_CURV = 0.36853024f;

typedef _Float16 h2 __attribute__((ext_vector_type(2)));

__device__ __forceinline__ unsigned pack_u32(float a, float b) {
    return __builtin_bit_cast(unsigned, __builtin_amdgcn_cvt_pkrtz(a, b));
}
__device__ __forceinline__ float fdot2f(h2 a, h2 b, float c) {
#if __has_builtin(__builtin_amdgcn_fdot2)
    return __builtin_amdgcn_fdot2(a, b, c, false);
#else
    return c + (float)a[0] * (float)b[0] + (float)a[1] * (float)b[1];
#endif
}

__host__ __device__ static inline int cdiv(int a, int b) { return (a + b - 1) / b; }

// basis from 10-bit quantized fractions; bb[t] matches TAP[t]
__device__ __forceinline__ void unpack_bb10(unsigned w1, float bb[8]) {
    const float s = 1.0f / 1023.0f;
    float f0 = (float)(w1 & 1023u) * s;
    float f1 = (float)((w1 >> 10) & 1023u) * s;
    float f2 = (float)((w1 >> 20) & 1023u) * s;
    float a0 = 1.f - f0, a1 = 1.f - f1, a2 = 1.f - f2;
    float p00 = a0 * a1, p10 = f0 * a1, p01 = a0 * f1, p11 = f0 * f1;
    bb[0] = p00 * a2; bb[1] = p10 * a2; bb[2] = p01 * a2; bb[3] = p11 * a2;
    bb[4] = p00 * f2; bb[5] = p10 * f2; bb[6] = p01 * f2; bb[7] = p11 * f2;
}

__device__ __forceinline__ void spline_wf(const float* __restrict__ a3,
                                          int& wib, float fr[3]) {
    int k[3];
#pragma unroll
    for (int d = 0; d < 3; ++d) {
        float p = fminf(fmaxf(a3[d], 0.f), 1.f) * 4.f;
        float f0 = fminf(floorf(p), 3.f);
        k[d] = (int)f0;
        fr[d] = p - f0;
    }
    wib = k[0] * 25 + k[1] * 5 + k[2];
}

// ---------- preamble kernels ----------

// dst histogram (counts pre-zeroed by memset) + x transform, one launch
__global__ void hist_tr(const float* __restrict__ x, float* __restrict__ h,
                        const int* __restrict__ dst, int* __restrict__ counts,
                        int N, int E) {
    int i = blockIdx.x * blockDim.x + threadIdx.x;
    if (i < E) atomicAdd(&counts[dst[i]], 1);
    if (i < N) {
        float t = (x[i] - LOWER_CURV) / (UPPER_CURV - LOWER_CURV) * 20.0f - 10.0f;
        h[i] = fminf(fmaxf(t, -10.0f), 10.0f);
    }
}

__global__ void scan_blocks(const int* __restrict__ counts, int* __restrict__ rowptr,
                            int* __restrict__ bsums, int n) {
    __shared__ int sh[256];
    int tid = threadIdx.x;
    int i = blockIdx.x * 256 + tid;
    int v = (i < n) ? counts[i] : 0;
    sh[tid] = v;
    __syncthreads();
    for (int off = 1; off < 256; off <<= 1) {
        int t = (tid >= off) ? sh[tid - off] : 0;
        __syncthreads();
        sh[tid] += t;
        __syncthreads();
    }
    if (i < n) rowptr[i] = sh[tid] - v;
    if (tid == 255) bsums[blockIdx.x] = sh[255];
}

// per-block redundant scan of bsums, then offset rowptr & init cursor (1 launch)
__global__ void add_offsets2(int* __restrict__ rowptr, const int* __restrict__ bsums,
                             int* __restrict__ cursor, int nb, int n, int E) {
    __shared__ int sh[256];
    int tid = threadIdx.x;
    int v = (tid < nb) ? bsums[tid] : 0;
    sh[tid] = v;
    __syncthreads();
    for (int off = 1; off < 256; off <<= 1) {
        int t = (tid >= off) ? sh[tid - off] : 0;
        __syncthreads();
        sh[tid] += t;
        __syncthreads();
    }
    int boff = (blockIdx.x == 0) ? 0 : sh[blockIdx.x - 1];
    int i = blockIdx.x * 256 + tid;
    if (i < n) {
        int r = rowptr[i] + boff;
        rowptr[i] = r;
        cursor[i] = r;
    }
    if (i == 0) rowptr[n] = E;
}

// chunk-local counting sort by wib (blocks < nchunk) + f16 weight-table prep
// (tail blocks). Records are 8B: w0 = src | wib<<18; w1 = q0|q1<<10|q2<<20.
__global__ __launch_bounds__(256) void scatter_prep(
        const int* __restrict__ src, const int* __restrict__ dst,
        const float* __restrict__ attr, int* __restrict__ cursor,
        uint2* __restrict__ records, uint2* __restrict__ records_d,
        int* __restrict__ iperm, int E, int nchunk,
        const float* __restrict__ W2, const float* __restrict__ W3,
        const float* __restrict__ W4, _Float16* __restrict__ wh2,
        _Float16* __restrict__ wh3, _Float16* __restrict__ wh4) {
    __shared__ int lh[KTOT], lbase[KTOT], lrank[KTOT];
    __shared__ int sb[128];
    const int tid = threadIdx.x;

    if ((int)blockIdx.x >= nchunk) {
        // ---- weight prep path: Wh[wi][(i>>3)][o][i&7] = W[wi][i][o] ----
        int idx = ((int)blockIdx.x - nchunk) * 256 + tid;   // < 64000
        const float* W; _Float16* Wh; int Cin, Cout, r;
        if (idx < 16000)      { W = W2; Wh = wh2; Cin = 8;  Cout = 16; r = idx; }
        else if (idx < 48000) { W = W3; Wh = wh3; Cin = 16; Cout = 16; r = idx - 16000; }
        else                  { W = W4; Wh = wh4; Cin = 16; Cout = 8;  r = idx - 48000; }
        int wi = r / (Cin * Cout);
        int q = r % (Cin * Cout);
        int i = q / Cout, o = q % Cout;
        Wh[wi * (Cin * Cout) + (i >> 3) * (8 * Cout) + o * 8 + (i & 7)] = (_Float16)W[r];
        return;
    }

    for (int i = tid; i < KTOT; i += 256) { lh[i] = 0; lrank[i] = 0; }
    __syncthreads();
    const int base = blockIdx.x * CHUNK;

    int wibs[8]; unsigned w1s[8];
#pragma unroll
    for (int k = 0; k < 8; ++k) {
        int e = base + tid + k * 256;
        wibs[k] = -1;
        if (e < E) {
            float a3[3] = {attr[e * 3], attr[e * 3 + 1], attr[e * 3 + 2]};
            int wib; float fr[3];
            spline_wf(a3, wib, fr);
            wibs[k] = wib;
            unsigned q0 = (unsigned)__float2int_rn(fr[0] * 1023.f);
            unsigned q1 = (unsigned)__float2int_rn(fr[1] * 1023.f);
            unsigned q2 = (unsigned)__float2int_rn(fr[2] * 1023.f);
            w1s[k] = q0 | (q1 << 10) | (q2 << 20);
            atomicAdd(&lh[wib], 1);
        }
    }
    __syncthreads();
    int v0 = 0;
    if (tid < 128) {
        v0 = (tid < KTOT) ? lh[tid] : 0;
        sb[tid] = v0;
    }
    __syncthreads();
    for (int off = 1; off < 128; off <<= 1) {
        int t = (tid >= off && tid < 128) ? sb[tid - off] : 0;
        __syncthreads();
        if (tid < 128) sb[tid] += t;
        __syncthreads();
    }
    if (tid < KTOT) lbase[tid] = sb[tid] - v0;
    __syncthreads();
#pragma unroll
    for (int k = 0; k < 8; ++k) {
        int e = base + tid + k * 256;
        if (e < E) {
            int w = wibs[k];
            int pos = base + lbase[w] + atomicAdd(&lrank[w], 1);
            uint2 rec = make_uint2((unsigned)src[e] | ((unsigned)w << 18), w1s[k]);
            records[pos] = rec;
            int p = atomicAdd(&cursor[dst[e]], 1);
            iperm[pos] = p;
            records_d[p] = rec;
        }
    }
}

// ---------- phase A: edge GEMM; reads f16 activations, writes y in dst-CSR order ----------
template<int Cin, int Cout>
__global__ __launch_bounds__(512) void edge_gemm(
        const uint2* __restrict__ records, const unsigned* __restrict__ xh,
        const _Float16* __restrict__ Wg, const int* __restrict__ iperm,
        _Float16* __restrict__ y, int E) {
    constexpr int SLOTS = 64 / Cout;
    constexpr int WH = KTOT * Cin * Cout;
    __shared__ __align__(16) _Float16 Wl[WH];
    for (int t = threadIdx.x; t < WH / 8; t += 512)
        ((uint4*)Wl)[t] = ((const uint4*)Wg)[t];
    __syncthreads();

    const int lane = threadIdx.x & 63;
    const int o = lane & (Cout - 1);
    const int slot = lane / Cout;
    const int wid = blockIdx.x * 8 + (threadIdx.x >> 6);
    const int stride = gridDim.x * 8;
    constexpr int TAP[8] = {0, 25, 5, 30, 1, 26, 6, 31};

    for (int base = wid * SLOTS; base < E; base += stride * SLOTS) {
        const int idx = base + slot;
        const bool act = idx < E;
        uint2 rec = act ? records[idx] : make_uint2(0u, 0u);
        int dpos = act ? iperm[idx] : 0;
        float bb[8];
        unpack_bb10(rec.y, bb);
        const int wib = (int)(rec.x >> 18);
        const unsigned sn = rec.x & 0x3FFFFu;

        h2 hx[Cin / 2];
        const uint4* xp = (const uint4*)(xh + (size_t)sn * (Cin / 2));
#pragma unroll
        for (int c = 0; c < Cin / 8; ++c) {
            uint4 q = xp[c];
            hx[4 * c + 0] = __builtin_bit_cast(h2, q.x);
            hx[4 * c + 1] = __builtin_bit_cast(h2, q.y);
            hx[4 * c + 2] = __builtin_bit_cast(h2, q.z);
            hx[4 * c + 3] = __builtin_bit_cast(h2, q.w);
        }
        float acc = 0.f;
#pragma unroll
        for (int t = 0; t < 8; ++t) {
            const int wi = wib + TAP[t];
            const _Float16* wp = &Wl[wi * (Cin * Cout) + o * 8];
            float dot = 0.f;
#pragma unroll
            for (int c = 0; c < Cin / 8; ++c) {
                union { uint4 u4; unsigned u[4]; } wu;
                wu.u4 = *(const uint4*)(wp + c * (8 * Cout));
                dot = fdot2f(hx[4 * c + 0], __builtin_bit_cast(h2, wu.u[0]), dot);
                dot = fdot2f(hx[4 * c + 1], __builtin_bit_cast(h2, wu.u[1]), dot);
                dot = fdot2f(hx[4 * c + 2], __builtin_bit_cast(h2, wu.u[2]), dot);
                dot = fdot2f(hx[4 * c + 3], __builtin_bit_cast(h2, wu.u[3]), dot);
            }
            acc = fmaf(bb[t], dot, acc);
        }
        if (act) y[(size_t)dpos * Cout + o] = (_Float16)acc;
    }
}

// ---------- phase B: sequential y reduce + root + ELU; writes f32 + packed f16 ----------
template<int Cin, int Cout>
__global__ void node_reduce(const int* __restrict__ rowptr,
                            const unsigned* __restrict__ yu,
                            const float* __restrict__ x,
                            const float* __restrict__ root,
                            const float* __restrict__ bias,
                            float* __restrict__ out, unsigned* __restrict__ xh,
                            int N) {
    constexpr int C2 = Cout / 2;
    int t = blockIdx.x * blockDim.x + threadIdx.x;
    int v = t / C2, o2 = t % C2;
    if (v >= N) return;
    int beg = rowptr[v], end = rowptr[v + 1];
    float a0 = 0.f, a1 = 0.f;
    for (int p = beg; p < end; ++p) {
        h2 hh = __builtin_bit_cast(h2, yu[(size_t)p * C2 + o2]);
        a0 += (float)hh[0];
        a1 += (float)hh[1];
    }
    const int o = 2 * o2;
    a0 += bias[o]; a1 += bias[o + 1];
#pragma unroll
    for (int i = 0; i < Cin; ++i) {
        float xv = x[(size_t)v * Cin + i];
        a0 = fmaf(xv, root[i * Cout + o], a0);
        a1 = fmaf(xv, root[i * Cout + o + 1], a1);
    }
    a0 = a0 > 0.f ? a0 : expm1f(a0);
    a1 = a1 > 0.f ? a1 : expm1f(a1);
    ((float2*)out)[(size_t)v * C2 + o2] = make_float2(a0, a1);
    xh[(size_t)v * C2 + o2] = pack_u32(a0, a1);
}

// ---------- fused small layers (records_d in dst-CSR order: contiguous reads) ----------

__global__ __launch_bounds__(512) void agg_l1(
        const int* __restrict__ rowptr, const uint2* __restrict__ records_d,
        const float* __restrict__ x, const float* __restrict__ W,
        const float* __restrict__ root, const float* __restrict__ bias,
        float* __restrict__ out, unsigned* __restrict__ xh2,
        int N, int totalWaves) {
    const int lane = threadIdx.x & 63;
    const int o = lane & 7;
    const int slot = lane >> 3;
    const int wid = blockIdx.x * 8 + (threadIdx.x >> 6);
    constexpr int TAP[8] = {0, 25, 5, 30, 1, 26, 6, 31};

    for (int v = wid; v < N; v += totalWaves) {
        const int beg = rowptr[v], end = rowptr[v + 1];
        float acc = 0.0f;
        for (int p0 = beg; p0 < end; p0 += 8) {
            const int p = p0 + slot;
            float xv = 0.f, bb[8];
            int wib = 0;
#pragma unroll
            for (int t = 0; t < 8; ++t) bb[t] = 0.f;
            if (p < end) {
                uint2 rec = records_d[p];
                unpack_bb10(rec.y, bb);
                wib = (int)(rec.x >> 18);
                xv = x[rec.x & 0x3FFFFu];
            }
#pragma unroll
            for (int t = 0; t < 8; ++t)
                acc = fmaf(bb[t] * xv, __ldg(&W[(wib + TAP[t]) * 8 + o]), acc);
        }
#pragma unroll
        for (int m = 8; m < 64; m <<= 1) acc += __shfl_xor(acc, m);
        if (slot == 0) {
            float z = acc + bias[o] + x[v] * root[o];
            z = z > 0.0f ? z : expm1f(z);
            out[(size_t)v * 8 + o] = z;
            float zp = __shfl_xor(z, 1);
            if ((o & 1) == 0) xh2[(size_t)v * 4 + (o >> 1)] = pack_u32(z, zp);
        }
    }
}

__global__ __launch_bounds__(512) void agg_l5(
        const int* __restrict__ rowptr, const uint2* __restrict__ records_d,
        const float* __restrict__ x, const float* __restrict__ W,
        const float* __restrict__ root, const float* __restrict__ bias,
        float* __restrict__ out, int N, int totalWaves) {
    const int lane = threadIdx.x & 63;
    const int i = lane & 7;
    const int slot = lane >> 3;
    const int wid = blockIdx.x * 8 + (threadIdx.x >> 6);
    constexpr int TAP[8] = {0, 25, 5, 30, 1, 26, 6, 31};

    for (int v = wid; v < N; v += totalWaves) {
        const int beg = rowptr[v], end = rowptr[v + 1];
        float acc = 0.0f;
        for (int p0 = beg; p0 < end; p0 += 8) {
            const int p = p0 + slot;
            float xi = 0.f, bb[8];
            int wib = 0;
#pragma unroll
            for (int t = 0; t < 8; ++t) bb[t] = 0.f;
            if (p < end) {
                uint2 rec = records_d[p];
                unpack_bb10(rec.y, bb);
                wib = (int)(rec.x >> 18);
                xi = x[(size_t)(rec.x & 0x3FFFFu) * 8 + i];
            }
#pragma unroll
            for (int t = 0; t < 8; ++t)
                acc = fmaf(bb[t] * xi, __ldg(&W[(wib + TAP[t]) * 8 + i]), acc);
        }
        if (slot == 0) acc = fmaf(x[(size_t)v * 8 + i], root[i], acc);
#pragma unroll
        for (int m = 1; m < 64; m <<= 1) acc += __shfl_xor(acc, m);
        if (lane == 0) {
            float z = acc + bias[0];
            out[v] = z > 0.0f ? z : expm1f(z);
        }
    }
}

// ---------- host ----------

static inline char* align256(char* p) {
    return (char*)(((uintptr_t)p + 255) & ~(uintptr_t)255);
}

extern "C" void kernel_launch(void* const* d_in, const int* in_sizes, int n_in,
                              void* d_out, int out_size, void* d_ws, size_t ws_size,
                              hipStream_t stream) {
    const float* x    = (const float*)d_in[0];
    const int*   ei   = (const int*)d_in[1];
    const float* attr = (const float*)d_in[2];
    const float* w[5]    = {(const float*)d_in[3],  (const float*)d_in[6],
                            (const float*)d_in[9],  (const float*)d_in[12],
                            (const float*)d_in[15]};
    const float* root[5] = {(const float*)d_in[4],  (const float*)d_in[7],
                            (const float*)d_in[10], (const float*)d_in[13],
                            (const float*)d_in[16]};
    const float* bias[5] = {(const float*)d_in[5],  (const float*)d_in[8],
                            (const float*)d_in[11], (const float*)d_in[14],
                            (const float*)d_in[17]};

    const int N = in_sizes[0];
    const int E = in_sizes[1] / 2;
    const int* src = ei;
    const int* dst = ei + E;

    char* ws = (char*)d_ws;
    float* bufA      = (float*)ws;    ws = align256(ws + (size_t)N * 16 * 4);
    float* bufB      = (float*)ws;    ws = align256(ws + (size_t)N * 16 * 4);
    int*   counts    = (int*)ws;      ws = align256(ws + (size_t)N * 4);
    int*   cursor    = (int*)ws;      ws = align256(ws + (size_t)N * 4);
    int*   rowptr    = (int*)ws;      ws = align256(ws + (size_t)(N + 1) * 4);
    int*   bsums     = (int*)ws;      ws = align256(ws + 256 * 4);
    uint2* records   = (uint2*)ws;    ws = align256(ws + (size_t)E * 8);
    uint2* records_d = (uint2*)ws;    ws = align256(ws + (size_t)E * 8);
    int*   iperm     = (int*)ws;      ws = align256(ws + (size_t)E * 4);
    _Float16* y      = (_Float16*)ws; ws = align256(ws + (size_t)E * 16 * 2);
    unsigned* xhA    = (unsigned*)ws; ws = align256(ws + (size_t)N * 8 * 4);
    unsigned* xhB    = (unsigned*)ws; ws = align256(ws + (size_t)N * 8 * 4);
    _Float16* wh2    = (_Float16*)ws; ws = align256(ws + (size_t)KTOT * 8 * 16 * 2);
    _Float16* wh3    = (_Float16*)ws; ws = align256(ws + (size_t)KTOT * 16 * 16 * 2);
    _Float16* wh4    = (_Float16*)ws; ws = align256(ws + (size_t)KTOT * 16 * 8 * 2);

    const int B = 256;
    const int nb = cdiv(N, 256);
    const int nchunk = cdiv(E, CHUNK);
    const int nprep = cdiv(64000, 256);
    const unsigned* yu = (const unsigned*)y;

    (void)hipMemsetAsync(counts, 0, (size_t)N * 4, stream);
    hist_tr<<<cdiv(E, B), B, 0, stream>>>(x, bufA, dst, counts, N, E);
    scan_blocks<<<nb, 256, 0, stream>>>(counts, rowptr, bsums, N);
    add_offsets2<<<nb, 256, 0, stream>>>(rowptr, bsums, cursor, nb, N, E);
    scatter_prep<<<nchunk + nprep, 256, 0, stream>>>(
        src, dst, attr, cursor, records, records_d, iperm, E, nchunk,
        w[1], w[2], w[3], wh2, wh3, wh4);

    const int GB = 512, TW = GB * 8;

    // L1 (1->8), fused; writes f32 out + f16 xhA
    agg_l1<<<GB, 512, 0, stream>>>(rowptr, records_d, bufA, w[0],
                                   root[0], bias[0], bufB, xhA, N, TW);
    // L2 (8->16)
    edge_gemm<8, 16><<<1024, 512, 0, stream>>>(records, xhA, wh2, iperm, y, E);
    node_reduce<8, 16><<<cdiv(N * 8, B), B, 0, stream>>>(rowptr, yu, bufB,
                                                         root[1], bias[1], bufA, xhB, N);
    // L3 (16->16)
    edge_gemm<16, 16><<<512, 512, 0, stream>>>(records, xhB, wh3, iperm, y, E);
    node_reduce<16, 16><<<cdiv(N * 8, B), B, 0, stream>>>(rowptr, yu, bufA,
                                                          root[2], bias[2], bufB, xhA, N);
    // L4 (16->8)
    edge_gemm<16, 8><<<1024, 512, 0, stream>>>(records, xhA, wh4, iperm, y, E);
    node_reduce<16, 8><<<cdiv(N * 4, B), B, 0, stream>>>(rowptr, yu, bufB,
                                                         root[3], bias[3], bufA, xhB, N);
    // L5 (8->1), fused
    agg_l5<<<GB, 512, 0, stream>>>(rowptr, records_d, bufA, w[4],
                                   root[4], bias[4], (float*)d_out, N, TW);
}

// Round 15
// 180.589 us; speedup vs baseline: 1.2547x; 1.1327x over previous
//
#include <hip/hip_runtime.h>
#include <math.h>

#define KSIZE 5
#define KTOT 125
#define CHUNK 2048

static constexpr float LOWER_CURV = -0.22703196f;
static constexpr float UPPER_CURV = 0.36853024f;

typedef _Float16 h2 __attribute__((ext_vector_type(2)));
typedef _Float16 h8_t __attribute__((ext_vector_type(8)));
typedef float f32x4 __attribute__((ext_vector_type(4)));

__device__ __forceinline__ unsigned pack_u32(float a, float b) {
    return __builtin_bit_cast(unsigned, __builtin_amdgcn_cvt_pkrtz(a, b));
}
__device__ __forceinline__ float fdot2f(h2 a, h2 b, float c) {
#if __has_builtin(__builtin_amdgcn_fdot2)
    return __builtin_amdgcn_fdot2(a, b, c, false);
#else
    return c + (float)a[0] * (float)b[0] + (float)a[1] * (float)b[1];
#endif
}

__host__ __device__ static inline int cdiv(int a, int b) { return (a + b - 1) / b; }

// basis from 10-bit quantized fractions; bb[t] matches TAP[t]
__device__ __forceinline__ void unpack_bb10(unsigned w1, float bb[8]) {
    const float s = 1.0f / 1023.0f;
    float f0 = (float)(w1 & 1023u) * s;
    float f1 = (float)((w1 >> 10) & 1023u) * s;
    float f2 = (float)((w1 >> 20) & 1023u) * s;
    float a0 = 1.f - f0, a1 = 1.f - f1, a2 = 1.f - f2;
    float p00 = a0 * a1, p10 = f0 * a1, p01 = a0 * f1, p11 = f0 * f1;
    bb[0] = p00 * a2; bb[1] = p10 * a2; bb[2] = p01 * a2; bb[3] = p11 * a2;
    bb[4] = p00 * f2; bb[5] = p10 * f2; bb[6] = p01 * f2; bb[7] = p11 * f2;
}

__device__ __forceinline__ void spline_wf(const float* __restrict__ a3,
                                          int& wib, float fr[3]) {
    int k[3];
#pragma unroll
    for (int d = 0; d < 3; ++d) {
        float p = fminf(fmaxf(a3[d], 0.f), 1.f) * 4.f;
        float f0 = fminf(floorf(p), 3.f);
        k[d] = (int)f0;
        fr[d] = p - f0;
    }
    wib = k[0] * 25 + k[1] * 5 + k[2];
}

// ---------- preamble kernels ----------

// x transform + dst histogram + block-aggregated wib histogram (counts/bcnt pre-zeroed)
__global__ __launch_bounds__(256) void hist_tr(
        const float* __restrict__ x, float* __restrict__ h,
        const int* __restrict__ dst, const float* __restrict__ attr,
        int* __restrict__ counts, int* __restrict__ bcnt, int N, int E) {
    __shared__ int lh[KTOT];
    const int tid = threadIdx.x;
    for (int i = tid; i < KTOT; i += 256) lh[i] = 0;
    __syncthreads();
    int i = blockIdx.x * 256 + tid;
    if (i < N) {
        float t = (x[i] - LOWER_CURV) / (UPPER_CURV - LOWER_CURV) * 20.0f - 10.0f;
        h[i] = fminf(fmaxf(t, -10.0f), 10.0f);
    }
    const int base = blockIdx.x * CHUNK;
#pragma unroll
    for (int k = 0; k < 8; ++k) {
        int e = base + tid + k * 256;
        if (e < E) {
            atomicAdd(&counts[dst[e]], 1);
            float a3[3] = {attr[e * 3], attr[e * 3 + 1], attr[e * 3 + 2]};
            int wib; float fr[3];
            spline_wf(a3, wib, fr);
            atomicAdd(&lh[wib], 1);
        }
    }
    __syncthreads();
    for (int j = tid; j < KTOT; j += 256) {
        int c = lh[j];
        if (c) atomicAdd(&bcnt[j], c);
    }
}

__global__ void scan_blocks(const int* __restrict__ counts, int* __restrict__ rowptr,
                            int* __restrict__ bsums, int n) {
    __shared__ int sh[256];
    int tid = threadIdx.x;
    int i = blockIdx.x * 256 + tid;
    int v = (i < n) ? counts[i] : 0;
    sh[tid] = v;
    __syncthreads();
    for (int off = 1; off < 256; off <<= 1) {
        int t = (tid >= off) ? sh[tid - off] : 0;
        __syncthreads();
        sh[tid] += t;
        __syncthreads();
    }
    if (i < n) rowptr[i] = sh[tid] - v;
    if (tid == 255) bsums[blockIdx.x] = sh[255];
}

// rowptr offset + cursor init; block 0 scans the 125 bucket counts PADDED TO 16
__global__ void add_offsets2(int* __restrict__ rowptr, const int* __restrict__ bsums,
                             int* __restrict__ cursor, const int* __restrict__ bcnt,
                             int* __restrict__ bases, int* __restrict__ bcursor,
                             int nb, int n, int E) {
    __shared__ int sh[256];
    __shared__ int sb[128];
    int tid = threadIdx.x;
    int v = (tid < nb) ? bsums[tid] : 0;
    sh[tid] = v;
    __syncthreads();
    for (int off = 1; off < 256; off <<= 1) {
        int t = (tid >= off) ? sh[tid - off] : 0;
        __syncthreads();
        sh[tid] += t;
        __syncthreads();
    }
    int boff = (blockIdx.x == 0) ? 0 : sh[blockIdx.x - 1];
    int i = blockIdx.x * 256 + tid;
    if (i < n) {
        int r = rowptr[i] + boff;
        rowptr[i] = r;
        cursor[i] = r;
    }
    if (i == 0) rowptr[n] = E;
    if (blockIdx.x == 0) {
        int cap = 0;
        if (tid < 128) {
            cap = (tid < KTOT) ? ((bcnt[tid] + 15) & ~15) : 0;
            sb[tid] = cap;
        }
        __syncthreads();
        for (int off = 1; off < 128; off <<= 1) {
            int t = (tid >= off && tid < 128) ? sb[tid - off] : 0;
            __syncthreads();
            if (tid < 128) sb[tid] += t;
            __syncthreads();
        }
        if (tid < KTOT) {
            int excl = sb[tid] - cap;
            bases[tid] = excl;
            bcursor[tid] = excl;
            if (tid == KTOT - 1) bases[KTOT] = excl + cap;
        }
    }
}

// GLOBAL bucket sort by wib (blocks < nchunk) + f16 weight-table prep
// (next nprep blocks) + pad fill (last KTOT blocks).
// Records 8B: w0 = src | wib<<18; w1 = q0|q1<<10|q2<<20.
__global__ __launch_bounds__(256) void scatter_prep(
        const int* __restrict__ src, const int* __restrict__ dst,
        const float* __restrict__ attr, int* __restrict__ cursor,
        int* __restrict__ bcursor, const int* __restrict__ bcnt,
        const int* __restrict__ bases,
        uint2* __restrict__ records, uint2* __restrict__ records_d,
        int* __restrict__ iperm, int E, int nchunk, int nprep,
        const float* __restrict__ W2, const float* __restrict__ W3,
        const float* __restrict__ W4, _Float16* __restrict__ wh2,
        _Float16* __restrict__ wh3, _Float16* __restrict__ wh4) {
    __shared__ int lh[KTOT], lbase[KTOT], lrank[KTOT];
    const int tid = threadIdx.x;

    if ((int)blockIdx.x >= nchunk + nprep) {
        // ---- pad fill: records in [bases[b]+bcnt[b], bases[b+1]) ----
        int b = (int)blockIdx.x - nchunk - nprep;
        int s = bases[b] + bcnt[b];
        int e = bases[b + 1];
        for (int i = s + tid; i < e; i += 256) {
            records[i] = make_uint2((unsigned)b << 18, 0u);
            iperm[i] = E;                // dump row
        }
        return;
    }
    if ((int)blockIdx.x >= nchunk) {
        // ---- weight prep: Wh[wi][(i>>3)][o][i&7] = W[wi][i][o] ----
        int idx = ((int)blockIdx.x - nchunk) * 256 + tid;   // < 64000 exactly
        const float* W; _Float16* Wh; int Cin, Cout, r;
        if (idx < 16000)      { W = W2; Wh = wh2; Cin = 8;  Cout = 16; r = idx; }
        else if (idx < 48000) { W = W3; Wh = wh3; Cin = 16; Cout = 16; r = idx - 16000; }
        else                  { W = W4; Wh = wh4; Cin = 16; Cout = 8;  r = idx - 48000; }
        int wi = r / (Cin * Cout);
        int q = r % (Cin * Cout);
        int i = q / Cout, o = q % Cout;
        Wh[wi * (Cin * Cout) + (i >> 3) * (8 * Cout) + o * 8 + (i & 7)] = (_Float16)W[r];
        return;
    }

    for (int i = tid; i < KTOT; i += 256) { lh[i] = 0; lrank[i] = 0; }
    __syncthreads();
    const int base = blockIdx.x * CHUNK;

    int wibs[8]; unsigned w1s[8];
#pragma unroll
    for (int k = 0; k < 8; ++k) {
        int e = base + tid + k * 256;
        wibs[k] = -1;
        if (e < E) {
            float a3[3] = {attr[e * 3], attr[e * 3 + 1], attr[e * 3 + 2]};
            int wib; float fr[3];
            spline_wf(a3, wib, fr);
            wibs[k] = wib;
            unsigned q0 = (unsigned)__float2int_rn(fr[0] * 1023.f);
            unsigned q1 = (unsigned)__float2int_rn(fr[1] * 1023.f);
            unsigned q2 = (unsigned)__float2int_rn(fr[2] * 1023.f);
            w1s[k] = q0 | (q1 << 10) | (q2 << 20);
            atomicAdd(&lh[wib], 1);
        }
    }
    __syncthreads();
    for (int i = tid; i < KTOT; i += 256) {
        int c = lh[i];
        lbase[i] = c ? atomicAdd(&bcursor[i], c) : 0;
    }
    __syncthreads();
#pragma unroll
    for (int k = 0; k < 8; ++k) {
        int e = base + tid + k * 256;
        if (e < E) {
            int w = wibs[k];
            int pos = lbase[w] + atomicAdd(&lrank[w], 1);
            uint2 rec = make_uint2((unsigned)src[e] | ((unsigned)w << 18), w1s[k]);
            records[pos] = rec;
            int p = atomicAdd(&cursor[dst[e]], 1);
            iperm[pos] = p;
            records_d[p] = rec;
        }
    }
}

// ---------- phase A (MFMA): 16-edge tiles, uniform wib, Cout=16 ----------
// y[e,o] = sum_k A[e,k] B[k,o];  A[e,(t,i)] = bb[t,e]*x[e,i],
// B[(t,i),o] = W[wib+TAP[t]][i][o].  One mfma_f32_16x16x32_f16 per K=32 slice.
template<int Cin>
__global__ __launch_bounds__(512) void edge_gemm_mfma(
        const uint2* __restrict__ records, const unsigned* __restrict__ xh,
        const _Float16* __restrict__ Wg, const int* __restrict__ iperm,
        _Float16* __restrict__ y, const int* __restrict__ epad_ptr) {
    constexpr int Cout = 16;
    constexpr int CC = Cin * Cout;
    constexpr int WH = KTOT * CC;
    constexpr int NM = Cin / 4;            // mfmas per tile (K=Cin*8 / 32)
    __shared__ __align__(16) _Float16 Wl[WH];
    for (int t = threadIdx.x; t < WH / 8; t += 512)
        ((uint4*)Wl)[t] = ((const uint4*)Wg)[t];
    __syncthreads();

    const int Ep = *epad_ptr;              // 16-aligned
    const int ntiles = Ep >> 4;
    const int lane = threadIdx.x & 63;
    const int o = lane & 15;               // edge-slot for A loads, out-col for B/D
    const int kb = lane >> 4;              // K-block 0..3
    const int chunk = (Cin == 16) ? (kb & 1) : 0;
    const int wid = blockIdx.x * 8 + (threadIdx.x >> 6);
    const int nwaves = gridDim.x * 8;
    constexpr int TAP[8] = {0, 25, 5, 30, 1, 26, 6, 31};

    for (int tile = wid; tile < ntiles; tile += nwaves) {
        const int tb = tile << 4;
        uint2 rec = records[tb + o];
        const int wib = (int)(((unsigned)__builtin_amdgcn_readfirstlane((int)rec.x)) >> 18);
        float bb[8];
        unpack_bb10(rec.y, bb);
        const unsigned sn = rec.x & 0x3FFFFu;
        uint4 xq = *(const uint4*)(xh + (size_t)sn * (Cin / 2) + chunk * 4);
        h2 xv[4];
        xv[0] = __builtin_bit_cast(h2, xq.x);
        xv[1] = __builtin_bit_cast(h2, xq.y);
        xv[2] = __builtin_bit_cast(h2, xq.z);
        xv[3] = __builtin_bit_cast(h2, xq.w);

        f32x4 acc = {0.f, 0.f, 0.f, 0.f};
#pragma unroll
        for (int m = 0; m < NM; ++m) {
            const int t = (Cin == 16) ? (2 * m + (kb >> 1)) : (4 * m + kb);
            const int wi = wib + TAP[t];
            _Float16 sh = (_Float16)bb[t];
            h2 ss; ss[0] = sh; ss[1] = sh;
            union { h8_t v; h2 h[4]; uint4 q; } A, B;
            A.h[0] = xv[0] * ss; A.h[1] = xv[1] * ss;
            A.h[2] = xv[2] * ss; A.h[3] = xv[3] * ss;
            B.q = *(const uint4*)&Wl[wi * CC + chunk * (8 * Cout) + o * 8];
            acc = __builtin_amdgcn_mfma_f32_16x16x32_f16(A.v, B.v, acc, 0, 0, 0);
        }
        // D: col = lane&15, row = kb*4 + r  (edge index within tile)
#pragma unroll
        for (int r = 0; r < 4; ++r) {
            int dp = iperm[tb + kb * 4 + r];
            y[(size_t)dp * 16 + o] = (_Float16)acc[r];
        }
    }
}

// ---------- phase A (fdot2): kept for L4 (Cout=8) ----------
template<int Cin, int Cout>
__global__ __launch_bounds__(512) void edge_gemm(
        const uint2* __restrict__ records, const unsigned* __restrict__ xh,
        const _Float16* __restrict__ Wg, const int* __restrict__ iperm,
        _Float16* __restrict__ y, const int* __restrict__ epad_ptr) {
    constexpr int SLOTS = 64 / Cout;
    constexpr int WH = KTOT * Cin * Cout;
    __shared__ __align__(16) _Float16 Wl[WH];
    for (int t = threadIdx.x; t < WH / 8; t += 512)
        ((uint4*)Wl)[t] = ((const uint4*)Wg)[t];
    __syncthreads();

    const int Ep = *epad_ptr;
    const int lane = threadIdx.x & 63;
    const int o = lane & (Cout - 1);
    const int slot = lane / Cout;
    const int wid = blockIdx.x * 8 + (threadIdx.x >> 6);
    const int stride = gridDim.x * 8;
    constexpr int TAP[8] = {0, 25, 5, 30, 1, 26, 6, 31};

    for (int base = wid * SLOTS; base < Ep; base += stride * SLOTS) {
        const int idx = base + slot;
        const bool act = idx < Ep;
        uint2 rec = act ? records[idx] : make_uint2(0u, 0u);
        int dpos = act ? iperm[idx] : 0;
        float bb[8];
        unpack_bb10(rec.y, bb);
        const int wib = (int)(rec.x >> 18);
        const unsigned sn = rec.x & 0x3FFFFu;

        h2 hx[Cin / 2];
        const uint4* xp = (const uint4*)(xh + (size_t)sn * (Cin / 2));
#pragma unroll
        for (int c = 0; c < Cin / 8; ++c) {
            uint4 q = xp[c];
            hx[4 * c + 0] = __builtin_bit_cast(h2, q.x);
            hx[4 * c + 1] = __builtin_bit_cast(h2, q.y);
            hx[4 * c + 2] = __builtin_bit_cast(h2, q.z);
            hx[4 * c + 3] = __builtin_bit_cast(h2, q.w);
        }
        float acc = 0.f;
#pragma unroll
        for (int t = 0; t < 8; ++t) {
            const int wi = wib + TAP[t];
            const _Float16* wp = &Wl[wi * (Cin * Cout) + o * 8];
            float dot = 0.f;
#pragma unroll
            for (int c = 0; c < Cin / 8; ++c) {
                union { uint4 u4; unsigned u[4]; } wu;
                wu.u4 = *(const uint4*)(wp + c * (8 * Cout));
                dot = fdot2f(hx[4 * c + 0], __builtin_bit_cast(h2, wu.u[0]), dot);
                dot = fdot2f(hx[4 * c + 1], __builtin_bit_cast(h2, wu.u[1]), dot);
                dot = fdot2f(hx[4 * c + 2], __builtin_bit_cast(h2, wu.u[2]), dot);
                dot = fdot2f(hx[4 * c + 3], __builtin_bit_cast(h2, wu.u[3]), dot);
            }
            acc = fmaf(bb[t], dot, acc);
        }
        if (act) y[(size_t)dpos * Cout + o] = (_Float16)acc;
    }
}

// ---------- phase B: sequential y reduce + root + ELU; writes f32 + packed f16 ----------
template<int Cin, int Cout>
__global__ void node_reduce(const int* __restrict__ rowptr,
                            const unsigned* __restrict__ yu,
                            const float* __restrict__ x,
                            const float* __restrict__ root,
                            const float* __restrict__ bias,
                            float* __restrict__ out, unsigned* __restrict__ xh,
                            int N) {
    constexpr int C2 = Cout / 2;
    int t = blockIdx.x * blockDim.x + threadIdx.x;
    int v = t / C2, o2 = t % C2;
    if (v >= N) return;
    int beg = rowptr[v], end = rowptr[v + 1];
    float a0 = 0.f, a1 = 0.f;
    for (int p = beg; p < end; ++p) {
        h2 hh = __builtin_bit_cast(h2, yu[(size_t)p * C2 + o2]);
        a0 += (float)hh[0];
        a1 += (float)hh[1];
    }
    const int o = 2 * o2;
    a0 += bias[o]; a1 += bias[o + 1];
#pragma unroll
    for (int i = 0; i < Cin; ++i) {
        float xv = x[(size_t)v * Cin + i];
        a0 = fmaf(xv, root[i * Cout + o], a0);
        a1 = fmaf(xv, root[i * Cout + o + 1], a1);
    }
    a0 = a0 > 0.f ? a0 : expm1f(a0);
    a1 = a1 > 0.f ? a1 : expm1f(a1);
    ((float2*)out)[(size_t)v * C2 + o2] = make_float2(a0, a1);
    xh[(size_t)v * C2 + o2] = pack_u32(a0, a1);
}

// ---------- fused small layers (records_d in dst-CSR order: contiguous reads) ----------

__global__ __launch_bounds__(512) void agg_l1(
        const int* __restrict__ rowptr, const uint2* __restrict__ records_d,
        const float* __restrict__ x, const float* __restrict__ W,
        const float* __restrict__ root, const float* __restrict__ bias,
        float* __restrict__ out, unsigned* __restrict__ xh2,
        int N, int totalWaves) {
    const int lane = threadIdx.x & 63;
    const int o = lane & 7;
    const int slot = lane >> 3;
    const int wid = blockIdx.x * 8 + (threadIdx.x >> 6);
    constexpr int TAP[8] = {0, 25, 5, 30, 1, 26, 6, 31};

    for (int v = wid; v < N; v += totalWaves) {
        const int beg = rowptr[v], end = rowptr[v + 1];
        float acc = 0.0f;
        for (int p0 = beg; p0 < end; p0 += 8) {
            const int p = p0 + slot;
            float xv = 0.f, bb[8];
            int wib = 0;
#pragma unroll
            for (int t = 0; t < 8; ++t) bb[t] = 0.f;
            if (p < end) {
                uint2 rec = records_d[p];
                unpack_bb10(rec.y, bb);
                wib = (int)(rec.x >> 18);
                xv = x[rec.x & 0x3FFFFu];
            }
#pragma unroll
            for (int t = 0; t < 8; ++t)
                acc = fmaf(bb[t] * xv, __ldg(&W[(wib + TAP[t]) * 8 + o]), acc);
        }
#pragma unroll
        for (int m = 8; m < 64; m <<= 1) acc += __shfl_xor(acc, m);
        if (slot == 0) {
            float z = acc + bias[o] + x[v] * root[o];
            z = z > 0.0f ? z : expm1f(z);
            out[(size_t)v * 8 + o] = z;
            float zp = __shfl_xor(z, 1);
            if ((o & 1) == 0) xh2[(size_t)v * 4 + (o >> 1)] = pack_u32(z, zp);
        }
    }
}

__global__ __launch_bounds__(512) void agg_l5(
        const int* __restrict__ rowptr, const uint2* __restrict__ records_d,
        const float* __restrict__ x, const float* __restrict__ W,
        const float* __restrict__ root, const float* __restrict__ bias,
        float* __restrict__ out, int N, int totalWaves) {
    const int lane = threadIdx.x & 63;
    const int i = lane & 7;
    const int slot = lane >> 3;
    const int wid = blockIdx.x * 8 + (threadIdx.x >> 6);
    constexpr int TAP[8] = {0, 25, 5, 30, 1, 26, 6, 31};

    for (int v = wid; v < N; v += totalWaves) {
        const int beg = rowptr[v], end = rowptr[v + 1];
        float acc = 0.0f;
        for (int p0 = beg; p0 < end; p0 += 8) {
            const int p = p0 + slot;
            float xi = 0.f, bb[8];
            int wib = 0;
#pragma unroll
            for (int t = 0; t < 8; ++t) bb[t] = 0.f;
            if (p < end) {
                uint2 rec = records_d[p];
                unpack_bb10(rec.y, bb);
                wib = (int)(rec.x >> 18);
                xi = x[(size_t)(rec.x & 0x3FFFFu) * 8 + i];
            }
#pragma unroll
            for (int t = 0; t < 8; ++t)
                acc = fmaf(bb[t] * xi, __ldg(&W[(wib + TAP[t]) * 8 + i]), acc);
        }
        if (slot == 0) acc = fmaf(x[(size_t)v * 8 + i], root[i], acc);
#pragma unroll
        for (int m = 1; m < 64; m <<= 1) acc += __shfl_xor(acc, m);
        if (lane == 0) {
            float z = acc + bias[0];
            out[v] = z > 0.0f ? z : expm1f(z);
        }
    }
}

// ---------- host ----------

static inline char* align256(char* p) {
    return (char*)(((uintptr_t)p + 255) & ~(uintptr_t)255);
}

extern "C" void kernel_launch(void* const* d_in, const int* in_sizes, int n_in,
                              void* d_out, int out_size, void* d_ws, size_t ws_size,
                              hipStream_t stream) {
    const float* x    = (const float*)d_in[0];
    const int*   ei   = (const int*)d_in[1];
    const float* attr = (const float*)d_in[2];
    const float* w[5]    = {(const float*)d_in[3],  (const float*)d_in[6],
                            (const float*)d_in[9],  (const float*)d_in[12],
                            (const float*)d_in[15]};
    const float* root[5] = {(const float*)d_in[4],  (const float*)d_in[7],
                            (const float*)d_in[10], (const float*)d_in[13],
                            (const float*)d_in[16]};
    const float* bias[5] = {(const float*)d_in[5],  (const float*)d_in[8],
                            (const float*)d_in[11], (const float*)d_in[14],
                            (const float*)d_in[17]};

    const int N = in_sizes[0];
    const int E = in_sizes[1] / 2;
    const int* src = ei;
    const int* dst = ei + E;
    const int EPCAP = E + 2048;     // capacity incl. bucket pads (<=125*15)

    char* ws = (char*)d_ws;
    float* bufA      = (float*)ws;    ws = align256(ws + (size_t)N * 16 * 4);
    float* bufB      = (float*)ws;    ws = align256(ws + (size_t)N * 16 * 4);
    int*   counts    = (int*)ws;      ws = align256(ws + (size_t)(N + 128) * 4);
    int*   bcnt      = counts + N;    // zeroed together with counts
    int*   cursor    = (int*)ws;      ws = align256(ws + (size_t)N * 4);
    int*   rowptr    = (int*)ws;      ws = align256(ws + (size_t)(N + 1) * 4);
    int*   bsums     = (int*)ws;      ws = align256(ws + 256 * 4);
    int*   bases     = (int*)ws;      ws = align256(ws + 128 * 4);
    int*   bcursor   = (int*)ws;      ws = align256(ws + 128 * 4);
    uint2* records   = (uint2*)ws;    ws = align256(ws + (size_t)EPCAP * 8);
    uint2* records_d = (uint2*)ws;    ws = align256(ws + (size_t)E * 8);
    int*   iperm     = (int*)ws;      ws = align256(ws + (size_t)EPCAP * 4);
    _Float16* y      = (_Float16*)ws; ws = align256(ws + (size_t)(E + 16) * 16 * 2);
    unsigned* xhA    = (unsigned*)ws; ws = align256(ws + (size_t)N * 8 * 4);
    unsigned* xhB    = (unsigned*)ws; ws = align256(ws + (size_t)N * 8 * 4);
    _Float16* wh2    = (_Float16*)ws; ws = align256(ws + (size_t)KTOT * 8 * 16 * 2);
    _Float16* wh3    = (_Float16*)ws; ws = align256(ws + (size_t)KTOT * 16 * 16 * 2);
    _Float16* wh4    = (_Float16*)ws; ws = align256(ws + (size_t)KTOT * 16 * 8 * 2);

    const int B = 256;
    const int nb = cdiv(N, 256);
    const int nchunk = cdiv(E, CHUNK);
    const int nprep = cdiv(64000, 256);
    const int* epad = bases + KTOT;
    const unsigned* yu = (const unsigned*)y;

    (void)hipMemsetAsync(counts, 0, (size_t)(N + 128) * 4, stream);
    hist_tr<<<nchunk, 256, 0, stream>>>(x, bufA, dst, attr, counts, bcnt, N, E);
    scan_blocks<<<nb, 256, 0, stream>>>(counts, rowptr, bsums, N);
    add_offsets2<<<nb, 256, 0, stream>>>(rowptr, bsums, cursor, bcnt, bases,
                                         bcursor, nb, N, E);
    scatter_prep<<<nchunk + nprep + KTOT, 256, 0, stream>>>(
        src, dst, attr, cursor, bcursor, bcnt, bases,
        records, records_d, iperm, E, nchunk, nprep,
        w[1], w[2], w[3], wh2, wh3, wh4);

    const int GB = 512, TW = GB * 8;

    // L1 (1->8), fused; writes f32 out + f16 xhA
    agg_l1<<<GB, 512, 0, stream>>>(rowptr, records_d, bufA, w[0],
                                   root[0], bias[0], bufB, xhA, N, TW);
    // L2 (8->16), MFMA
    edge_gemm_mfma<8><<<GB, 512, 0, stream>>>(records, xhA, wh2, iperm, y, epad);
    node_reduce<8, 16><<<cdiv(N * 8, B), B, 0, stream>>>(rowptr, yu, bufB,
                                                         root[1], bias[1], bufA, xhB, N);
    // L3 (16->16), MFMA
    edge_gemm_mfma<16><<<GB, 512, 0, stream>>>(records, xhB, wh3, iperm, y, epad);
    node_reduce<16, 16><<<cdiv(N * 8, B), B, 0, stream>>>(rowptr, yu, bufA,
                                                          root[2], bias[2], bufB, xhA, N);
    // L4 (16->8), fdot2
    edge_gemm<16, 8><<<1024, 512, 0, stream>>>(records, xhA, wh4, iperm, y, epad);
    node_reduce<16, 8><<<cdiv(N * 4, B), B, 0, stream>>>(rowptr, yu, bufB,
                                                         root[3], bias[3], bufA, xhB, N);
    // L5 (8->1), fused
    agg_l5<<<GB, 512, 0, stream>>>(rowptr, records_d, bufA, w[4],
                                   root[4], bias[4], (float*)d_out, N, TW);
}

// Round 16
// 176.235 us; speedup vs baseline: 1.2857x; 1.0247x over previous
//
#include <hip/hip_runtime.h>
#include <math.h>

#define KSIZE 5
#define KTOT 125
#define CHUNK 2048

static constexpr float LOWER_CURV = -0.22703196f;
static constexpr float UPPER_CURV = 0.36853024f;

typedef _Float16 h2 __attribute__((ext_vector_type(2)));
typedef _Float16 h8_t __attribute__((ext_vector_type(8)));
typedef float f32x4 __attribute__((ext_vector_type(4)));

__device__ __forceinline__ unsigned pack_u32(float a, float b) {
    return __builtin_bit_cast(unsigned, __builtin_amdgcn_cvt_pkrtz(a, b));
}

__host__ __device__ static inline int cdiv(int a, int b) { return (a + b - 1) / b; }

// basis from 10-bit quantized fractions; bb[t] matches TAP[t]
__device__ __forceinline__ void unpack_bb10(unsigned w1, float bb[8]) {
    const float s = 1.0f / 1023.0f;
    float f0 = (float)(w1 & 1023u) * s;
    float f1 = (float)((w1 >> 10) & 1023u) * s;
    float f2 = (float)((w1 >> 20) & 1023u) * s;
    float a0 = 1.f - f0, a1 = 1.f - f1, a2 = 1.f - f2;
    float p00 = a0 * a1, p10 = f0 * a1, p01 = a0 * f1, p11 = f0 * f1;
    bb[0] = p00 * a2; bb[1] = p10 * a2; bb[2] = p01 * a2; bb[3] = p11 * a2;
    bb[4] = p00 * f2; bb[5] = p10 * f2; bb[6] = p01 * f2; bb[7] = p11 * f2;
}

__device__ __forceinline__ void spline_wf(const float* __restrict__ a3,
                                          int& wib, float fr[3]) {
    int k[3];
#pragma unroll
    for (int d = 0; d < 3; ++d) {
        float p = fminf(fmaxf(a3[d], 0.f), 1.f) * 4.f;
        float f0 = fminf(floorf(p), 3.f);
        k[d] = (int)f0;
        fr[d] = p - f0;
    }
    wib = k[0] * 25 + k[1] * 5 + k[2];
}

// ---------- preamble kernels ----------

// x transform + dst histogram + block-aggregated wib histogram (counts/bcnt pre-zeroed)
__global__ __launch_bounds__(256) void hist_tr(
        const float* __restrict__ x, float* __restrict__ h,
        const int* __restrict__ dst, const float* __restrict__ attr,
        int* __restrict__ counts, int* __restrict__ bcnt, int N, int E) {
    __shared__ int lh[KTOT];
    const int tid = threadIdx.x;
    for (int i = tid; i < KTOT; i += 256) lh[i] = 0;
    __syncthreads();
    int i = blockIdx.x * 256 + tid;
    if (i < N) {
        float t = (x[i] - LOWER_CURV) / (UPPER_CURV - LOWER_CURV) * 20.0f - 10.0f;
        h[i] = fminf(fmaxf(t, -10.0f), 10.0f);
    }
    const int base = blockIdx.x * CHUNK;
#pragma unroll
    for (int k = 0; k < 8; ++k) {
        int e = base + tid + k * 256;
        if (e < E) {
            atomicAdd(&counts[dst[e]], 1);
            float a3[3] = {attr[e * 3], attr[e * 3 + 1], attr[e * 3 + 2]};
            int wib; float fr[3];
            spline_wf(a3, wib, fr);
            atomicAdd(&lh[wib], 1);
        }
    }
    __syncthreads();
    for (int j = tid; j < KTOT; j += 256) {
        int c = lh[j];
        if (c) atomicAdd(&bcnt[j], c);
    }
}

__global__ void scan_blocks(const int* __restrict__ counts, int* __restrict__ rowptr,
                            int* __restrict__ bsums, int n) {
    __shared__ int sh[256];
    int tid = threadIdx.x;
    int i = blockIdx.x * 256 + tid;
    int v = (i < n) ? counts[i] : 0;
    sh[tid] = v;
    __syncthreads();
    for (int off = 1; off < 256; off <<= 1) {
        int t = (tid >= off) ? sh[tid - off] : 0;
        __syncthreads();
        sh[tid] += t;
        __syncthreads();
    }
    if (i < n) rowptr[i] = sh[tid] - v;
    if (tid == 255) bsums[blockIdx.x] = sh[255];
}

// rowptr offset + cursor init; block 0 scans the 125 bucket counts PADDED TO 16
__global__ void add_offsets2(int* __restrict__ rowptr, const int* __restrict__ bsums,
                             int* __restrict__ cursor, const int* __restrict__ bcnt,
                             int* __restrict__ bases, int* __restrict__ bcursor,
                             int nb, int n, int E) {
    __shared__ int sh[256];
    __shared__ int sb[128];
    int tid = threadIdx.x;
    int v = (tid < nb) ? bsums[tid] : 0;
    sh[tid] = v;
    __syncthreads();
    for (int off = 1; off < 256; off <<= 1) {
        int t = (tid >= off) ? sh[tid - off] : 0;
        __syncthreads();
        sh[tid] += t;
        __syncthreads();
    }
    int boff = (blockIdx.x == 0) ? 0 : sh[blockIdx.x - 1];
    int i = blockIdx.x * 256 + tid;
    if (i < n) {
        int r = rowptr[i] + boff;
        rowptr[i] = r;
        cursor[i] = r;
    }
    if (i == 0) rowptr[n] = E;
    if (blockIdx.x == 0) {
        int cap = 0;
        if (tid < 128) {
            cap = (tid < KTOT) ? ((bcnt[tid] + 15) & ~15) : 0;
            sb[tid] = cap;
        }
        __syncthreads();
        for (int off = 1; off < 128; off <<= 1) {
            int t = (tid >= off && tid < 128) ? sb[tid - off] : 0;
            __syncthreads();
            if (tid < 128) sb[tid] += t;
            __syncthreads();
        }
        if (tid < KTOT) {
            int excl = sb[tid] - cap;
            bases[tid] = excl;
            bcursor[tid] = excl;
            if (tid == KTOT - 1) bases[KTOT] = excl + cap;
        }
    }
}

// GLOBAL bucket sort by wib (blocks < nchunk) + f16 weight-table prep
// (next nprep blocks; wh4 zero-padded to 16 cols) + pad fill (last KTOT blocks).
// Records 8B: w0 = src | wib<<18; w1 = q0|q1<<10|q2<<20.
__global__ __launch_bounds__(256) void scatter_prep(
        const int* __restrict__ src, const int* __restrict__ dst,
        const float* __restrict__ attr, int* __restrict__ cursor,
        int* __restrict__ bcursor, const int* __restrict__ bcnt,
        const int* __restrict__ bases,
        uint2* __restrict__ records, uint2* __restrict__ records_d,
        int* __restrict__ iperm, int E, int nchunk, int nprep,
        const float* __restrict__ W2, const float* __restrict__ W3,
        const float* __restrict__ W4, _Float16* __restrict__ wh2,
        _Float16* __restrict__ wh3, _Float16* __restrict__ wh4) {
    __shared__ int lh[KTOT], lbase[KTOT], lrank[KTOT];
    const int tid = threadIdx.x;

    if ((int)blockIdx.x >= nchunk + nprep) {
        // ---- pad fill: records in [bases[b]+bcnt[b], bases[b+1]) ----
        int b = (int)blockIdx.x - nchunk - nprep;
        int s = bases[b] + bcnt[b];
        int e = bases[b + 1];
        for (int i = s + tid; i < e; i += 256) {
            records[i] = make_uint2((unsigned)b << 18, 0u);
            iperm[i] = E;                // dump row
        }
        return;
    }
    if ((int)blockIdx.x >= nchunk) {
        // ---- weight prep: Wh[wi][(i>>3)][o][i&7] = W[wi][i][o] ----
        int idx = ((int)blockIdx.x - nchunk) * 256 + tid;   // < 80000
        if (idx >= 80000) return;
        if (idx < 16000) {
            // wh2: Cin=8, Cout=16
            int wi = idx / 128, q = idx % 128;
            int i = q / 16, o = q % 16;
            wh2[wi * 128 + o * 8 + i] = (_Float16)W2[idx];
        } else if (idx < 48000) {
            // wh3: Cin=16, Cout=16
            int r = idx - 16000;
            int wi = r / 256, q = r % 256;
            int i = q / 16, o = q % 16;
            wh3[wi * 256 + (i >> 3) * 128 + o * 8 + (i & 7)] = (_Float16)W3[r];
        } else {
            // wh4: Cin=16, Cout padded 8->16 (zeros for o>=8)
            int r = idx - 48000;                 // < 32000 = 125*16*16
            int wi = r / 256, q = r % 256;
            int i = q / 16, o = q % 16;
            float val = (o < 8) ? W4[(wi * 16 + i) * 8 + o] : 0.0f;
            wh4[wi * 256 + (i >> 3) * 128 + o * 8 + (i & 7)] = (_Float16)val;
        }
        return;
    }

    for (int i = tid; i < KTOT; i += 256) { lh[i] = 0; lrank[i] = 0; }
    __syncthreads();
    const int base = blockIdx.x * CHUNK;

    int wibs[8]; unsigned w1s[8];
#pragma unroll
    for (int k = 0; k < 8; ++k) {
        int e = base + tid + k * 256;
        wibs[k] = -1;
        if (e < E) {
            float a3[3] = {attr[e * 3], attr[e * 3 + 1], attr[e * 3 + 2]};
            int wib; float fr[3];
            spline_wf(a3, wib, fr);
            wibs[k] = wib;
            unsigned q0 = (unsigned)__float2int_rn(fr[0] * 1023.f);
            unsigned q1 = (unsigned)__float2int_rn(fr[1] * 1023.f);
            unsigned q2 = (unsigned)__float2int_rn(fr[2] * 1023.f);
            w1s[k] = q0 | (q1 << 10) | (q2 << 20);
            atomicAdd(&lh[wib], 1);
        }
    }
    __syncthreads();
    for (int i = tid; i < KTOT; i += 256) {
        int c = lh[i];
        lbase[i] = c ? atomicAdd(&bcursor[i], c) : 0;
    }
    __syncthreads();
#pragma unroll
    for (int k = 0; k < 8; ++k) {
        int e = base + tid + k * 256;
        if (e < E) {
            int w = wibs[k];
            int pos = lbase[w] + atomicAdd(&lrank[w], 1);
            uint2 rec = make_uint2((unsigned)src[e] | ((unsigned)w << 18), w1s[k]);
            records[pos] = rec;
            int p = atomicAdd(&cursor[dst[e]], 1);
            iperm[pos] = p;
            records_d[p] = rec;
        }
    }
}

// ---------- phase A (MFMA): 16-edge tiles, uniform wib ----------
// y[e,o] = sum_k A[e,k] B[k,o];  A[e,(t,i)] = bb[t,e]*x[e,i],
// B[(t,i),o] = W[wib+TAP[t]][i][o].  One mfma_f32_16x16x32_f16 per K=32 slice.
// CR = real output channels (y stride); B padded to 16 cols when CR<16.
template<int Cin, int CR>
__global__ __launch_bounds__(512) void edge_gemm_mfma(
        const uint2* __restrict__ records, const unsigned* __restrict__ xh,
        const _Float16* __restrict__ Wg, const int* __restrict__ iperm,
        _Float16* __restrict__ y, const int* __restrict__ epad_ptr) {
    constexpr int Cout = 16;
    constexpr int CC = Cin * Cout;
    constexpr int WH = KTOT * CC;
    constexpr int NM = Cin / 4;            // mfmas per tile (K=Cin*8 / 32)
    __shared__ __align__(16) _Float16 Wl[WH];
    for (int t = threadIdx.x; t < WH / 8; t += 512)
        ((uint4*)Wl)[t] = ((const uint4*)Wg)[t];
    __syncthreads();

    const int Ep = *epad_ptr;              // 16-aligned
    const int ntiles = Ep >> 4;
    const int lane = threadIdx.x & 63;
    const int o = lane & 15;               // edge-slot for A loads, out-col for B/D
    const int kb = lane >> 4;              // K-block 0..3
    const int chunk = (Cin == 16) ? (kb & 1) : 0;
    const int wid = blockIdx.x * 8 + (threadIdx.x >> 6);
    const int nwaves = gridDim.x * 8;
    constexpr int TAP[8] = {0, 25, 5, 30, 1, 26, 6, 31};

    for (int tile = wid; tile < ntiles; tile += nwaves) {
        const int tb = tile << 4;
        uint2 rec = records[tb + o];
        const int wib = (int)(((unsigned)__builtin_amdgcn_readfirstlane((int)rec.x)) >> 18);
        float bb[8];
        unpack_bb10(rec.y, bb);
        const unsigned sn = rec.x & 0x3FFFFu;
        uint4 xq = *(const uint4*)(xh + (size_t)sn * (Cin / 2) + chunk * 4);
        h2 xv[4];
        xv[0] = __builtin_bit_cast(h2, xq.x);
        xv[1] = __builtin_bit_cast(h2, xq.y);
        xv[2] = __builtin_bit_cast(h2, xq.z);
        xv[3] = __builtin_bit_cast(h2, xq.w);

        f32x4 acc = {0.f, 0.f, 0.f, 0.f};
#pragma unroll
        for (int m = 0; m < NM; ++m) {
            const int t = (Cin == 16) ? (2 * m + (kb >> 1)) : (4 * m + kb);
            const int wi = wib + TAP[t];
            _Float16 sh = (_Float16)bb[t];
            h2 ss; ss[0] = sh; ss[1] = sh;
            union { h8_t v; h2 h[4]; uint4 q; } A, B;
            A.h[0] = xv[0] * ss; A.h[1] = xv[1] * ss;
            A.h[2] = xv[2] * ss; A.h[3] = xv[3] * ss;
            B.q = *(const uint4*)&Wl[wi * CC + chunk * (8 * Cout) + o * 8];
            acc = __builtin_amdgcn_mfma_f32_16x16x32_f16(A.v, B.v, acc, 0, 0, 0);
        }
        // D: col = lane&15, row = kb*4 + r  (edge index within tile)
        if (CR == 16 || o < CR) {
#pragma unroll
            for (int r = 0; r < 4; ++r) {
                int dp = iperm[tb + kb * 4 + r];
                y[(size_t)dp * CR + o] = (_Float16)acc[r];
            }
        }
    }
}

// ---------- phase B: sequential y reduce + root + ELU; writes f32 + packed f16 ----------
template<int Cin, int Cout>
__global__ void node_reduce(const int* __restrict__ rowptr,
                            const unsigned* __restrict__ yu,
                            const float* __restrict__ x,
                            const float* __restrict__ root,
                            const float* __restrict__ bias,
                            float* __restrict__ out, unsigned* __restrict__ xh,
                            int N) {
    constexpr int C2 = Cout / 2;
    int t = blockIdx.x * blockDim.x + threadIdx.x;
    int v = t / C2, o2 = t % C2;
    if (v >= N) return;
    int beg = rowptr[v], end = rowptr[v + 1];
    float a0 = 0.f, a1 = 0.f;
    for (int p = beg; p < end; ++p) {
        h2 hh = __builtin_bit_cast(h2, yu[(size_t)p * C2 + o2]);
        a0 += (float)hh[0];
        a1 += (float)hh[1];
    }
    const int o = 2 * o2;
    a0 += bias[o]; a1 += bias[o + 1];
#pragma unroll
    for (int i = 0; i < Cin; ++i) {
        float xv = x[(size_t)v * Cin + i];
        a0 = fmaf(xv, root[i * Cout + o], a0);
        a1 = fmaf(xv, root[i * Cout + o + 1], a1);
    }
    a0 = a0 > 0.f ? a0 : expm1f(a0);
    a1 = a1 > 0.f ? a1 : expm1f(a1);
    ((float2*)out)[(size_t)v * C2 + o2] = make_float2(a0, a1);
    xh[(size_t)v * C2 + o2] = pack_u32(a0, a1);
}

// ---------- fused small layers (records_d in dst-CSR order: contiguous reads) ----------

__global__ __launch_bounds__(512) void agg_l1(
        const int* __restrict__ rowptr, const uint2* __restrict__ records_d,
        const float* __restrict__ x, const float* __restrict__ W,
        const float* __restrict__ root, const float* __restrict__ bias,
        float* __restrict__ out, unsigned* __restrict__ xh2,
        int N, int totalWaves) {
    const int lane = threadIdx.x & 63;
    const int o = lane & 7;
    const int slot = lane >> 3;
    const int wid = blockIdx.x * 8 + (threadIdx.x >> 6);
    constexpr int TAP[8] = {0, 25, 5, 30, 1, 26, 6, 31};

    for (int v = wid; v < N; v += totalWaves) {
        const int beg = rowptr[v], end = rowptr[v + 1];
        float acc = 0.0f;
        for (int p0 = beg; p0 < end; p0 += 8) {
            const int p = p0 + slot;
            float xv = 0.f, bb[8];
            int wib = 0;
#pragma unroll
            for (int t = 0; t < 8; ++t) bb[t] = 0.f;
            if (p < end) {
                uint2 rec = records_d[p];
                unpack_bb10(rec.y, bb);
                wib = (int)(rec.x >> 18);
                xv = x[rec.x & 0x3FFFFu];
            }
#pragma unroll
            for (int t = 0; t < 8; ++t)
                acc = fmaf(bb[t] * xv, __ldg(&W[(wib + TAP[t]) * 8 + o]), acc);
        }
#pragma unroll
        for (int m = 8; m < 64; m <<= 1) acc += __shfl_xor(acc, m);
        if (slot == 0) {
            float z = acc + bias[o] + x[v] * root[o];
            z = z > 0.0f ? z : expm1f(z);
            out[(size_t)v * 8 + o] = z;
            float zp = __shfl_xor(z, 1);
            if ((o & 1) == 0) xh2[(size_t)v * 4 + (o >> 1)] = pack_u32(z, zp);
        }
    }
}

__global__ __launch_bounds__(512) void agg_l5(
        const int* __restrict__ rowptr, const uint2* __restrict__ records_d,
        const float* __restrict__ x, const float* __restrict__ W,
        const float* __restrict__ root, const float* __restrict__ bias,
        float* __restrict__ out, int N, int totalWaves) {
    const int lane = threadIdx.x & 63;
    const int i = lane & 7;
    const int slot = lane >> 3;
    const int wid = blockIdx.x * 8 + (threadIdx.x >> 6);
    constexpr int TAP[8] = {0, 25, 5, 30, 1, 26, 6, 31};

    for (int v = wid; v < N; v += totalWaves) {
        const int beg = rowptr[v], end = rowptr[v + 1];
        float acc = 0.0f;
        for (int p0 = beg; p0 < end; p0 += 8) {
            const int p = p0 + slot;
            float xi = 0.f, bb[8];
            int wib = 0;
#pragma unroll
            for (int t = 0; t < 8; ++t) bb[t] = 0.f;
            if (p < end) {
                uint2 rec = records_d[p];
                unpack_bb10(rec.y, bb);
                wib = (int)(rec.x >> 18);
                xi = x[(size_t)(rec.x & 0x3FFFFu) * 8 + i];
            }
#pragma unroll
            for (int t = 0; t < 8; ++t)
                acc = fmaf(bb[t] * xi, __ldg(&W[(wib + TAP[t]) * 8 + i]), acc);
        }
        if (slot == 0) acc = fmaf(x[(size_t)v * 8 + i], root[i], acc);
#pragma unroll
        for (int m = 1; m < 64; m <<= 1) acc += __shfl_xor(acc, m);
        if (lane == 0) {
            float z = acc + bias[0];
            out[v] = z > 0.0f ? z : expm1f(z);
        }
    }
}

// ---------- host ----------

static inline char* align256(char* p) {
    return (char*)(((uintptr_t)p + 255) & ~(uintptr_t)255);
}

extern "C" void kernel_launch(void* const* d_in, const int* in_sizes, int n_in,
                              void* d_out, int out_size, void* d_ws, size_t ws_size,
                              hipStream_t stream) {
    const float* x    = (const float*)d_in[0];
    const int*   ei   = (const int*)d_in[1];
    const float* attr = (const float*)d_in[2];
    const float* w[5]    = {(const float*)d_in[3],  (const float*)d_in[6],
                            (const float*)d_in[9],  (const float*)d_in[12],
                            (const float*)d_in[15]};
    const float* root[5] = {(const float*)d_in[4],  (const float*)d_in[7],
                            (const float*)d_in[10], (const float*)d_in[13],
                            (const float*)d_in[16]};
    const float* bias[5] = {(const float*)d_in[5],  (const float*)d_in[8],
                            (const float*)d_in[11], (const float*)d_in[14],
                            (const float*)d_in[17]};

    const int N = in_sizes[0];
    const int E = in_sizes[1] / 2;
    const int* src = ei;
    const int* dst = ei + E;
    const int EPCAP = E + 2048;     // capacity incl. bucket pads (<=125*15)

    char* ws = (char*)d_ws;
    float* bufA      = (float*)ws;    ws = align256(ws + (size_t)N * 16 * 4);
    float* bufB      = (float*)ws;    ws = align256(ws + (size_t)N * 16 * 4);
    int*   counts    = (int*)ws;      ws = align256(ws + (size_t)(N + 128) * 4);
    int*   bcnt      = counts + N;    // zeroed together with counts
    int*   cursor    = (int*)ws;      ws = align256(ws + (size_t)N * 4);
    int*   rowptr    = (int*)ws;      ws = align256(ws + (size_t)(N + 1) * 4);
    int*   bsums     = (int*)ws;      ws = align256(ws + 256 * 4);
    int*   bases     = (int*)ws;      ws = align256(ws + 128 * 4);
    int*   bcursor   = (int*)ws;      ws = align256(ws + 128 * 4);
    uint2* records   = (uint2*)ws;    ws = align256(ws + (size_t)EPCAP * 8);
    uint2* records_d = (uint2*)ws;    ws = align256(ws + (size_t)E * 8);
    int*   iperm     = (int*)ws;      ws = align256(ws + (size_t)EPCAP * 4);
    _Float16* y      = (_Float16*)ws; ws = align256(ws + (size_t)(E + 16) * 16 * 2);
    unsigned* xhA    = (unsigned*)ws; ws = align256(ws + (size_t)N * 8 * 4);
    unsigned* xhB    = (unsigned*)ws; ws = align256(ws + (size_t)N * 8 * 4);
    _Float16* wh2    = (_Float16*)ws; ws = align256(ws + (size_t)KTOT * 8 * 16 * 2);
    _Float16* wh3    = (_Float16*)ws; ws = align256(ws + (size_t)KTOT * 16 * 16 * 2);
    _Float16* wh4    = (_Float16*)ws; ws = align256(ws + (size_t)KTOT * 16 * 16 * 2); // padded

    const int B = 256;
    const int nb = cdiv(N, 256);
    const int nchunk = cdiv(E, CHUNK);
    const int nprep = cdiv(80000, 256);
    const int* epad = bases + KTOT;
    const unsigned* yu = (const unsigned*)y;

    (void)hipMemsetAsync(counts, 0, (size_t)(N + 128) * 4, stream);
    hist_tr<<<nchunk, 256, 0, stream>>>(x, bufA, dst, attr, counts, bcnt, N, E);
    scan_blocks<<<nb, 256, 0, stream>>>(counts, rowptr, bsums, N);
    add_offsets2<<<nb, 256, 0, stream>>>(rowptr, bsums, cursor, bcnt, bases,
                                         bcursor, nb, N, E);
    scatter_prep<<<nchunk + nprep + KTOT, 256, 0, stream>>>(
        src, dst, attr, cursor, bcursor, bcnt, bases,
        records, records_d, iperm, E, nchunk, nprep,
        w[1], w[2], w[3], wh2, wh3, wh4);

    const int GB = 512, TW = GB * 8;

    // L1 (1->8), fused; writes f32 out + f16 xhA
    agg_l1<<<GB, 512, 0, stream>>>(rowptr, records_d, bufA, w[0],
                                   root[0], bias[0], bufB, xhA, N, TW);
    // L2 (8->16), MFMA
    edge_gemm_mfma<8, 16><<<GB, 512, 0, stream>>>(records, xhA, wh2, iperm, y, epad);
    node_reduce<8, 16><<<cdiv(N * 8, B), B, 0, stream>>>(rowptr, yu, bufB,
                                                         root[1], bias[1], bufA, xhB, N);
    // L3 (16->16), MFMA
    edge_gemm_mfma<16, 16><<<GB, 512, 0, stream>>>(records, xhB, wh3, iperm, y, epad);
    node_reduce<16, 16><<<cdiv(N * 8, B), B, 0, stream>>>(rowptr, yu, bufA,
                                                          root[2], bias[2], bufB, xhA, N);
    // L4 (16->8), MFMA with padded B (8 real cols)
    edge_gemm_mfma<16, 8><<<GB, 512, 0, stream>>>(records, xhA, wh4, iperm, y, epad);
    node_reduce<16, 8><<<cdiv(N * 4, B), B, 0, stream>>>(rowptr, yu, bufB,
                                                         root[3], bias[3], bufA, xhB, N);
    // L5 (8->1), fused
    agg_l5<<<GB, 512, 0, stream>>>(rowptr, records_d, bufA, w[4],
                                   root[4], bias[4], (float*)d_out, N, TW);
}

// Round 17
// 175.465 us; speedup vs baseline: 1.2913x; 1.0044x over previous
//
#include <hip/hip_runtime.h>
#include <math.h>

#define KSIZE 5
#define KTOT 125
#define CHUNK 2048

static constexpr float LOWER_CURV = -0.22703196f;
static constexpr float UPPER_CURV = 0.36853024f;

typedef _Float16 h2 __attribute__((ext_vector_type(2)));
typedef _Float16 h8_t __attribute__((ext_vector_type(8)));
typedef float f32x4 __attribute__((ext_vector_type(4)));

__device__ __forceinline__ unsigned pack_u32(float a, float b) {
    return __builtin_bit_cast(unsigned, __builtin_amdgcn_cvt_pkrtz(a, b));
}

__host__ __device__ static inline int cdiv(int a, int b) { return (a + b - 1) / b; }

// basis from 10-bit quantized fractions; bb[t] matches TAP[t]
__device__ __forceinline__ void unpack_bb10(unsigned w1, float bb[8]) {
    const float s = 1.0f / 1023.0f;
    float f0 = (float)(w1 & 1023u) * s;
    float f1 = (float)((w1 >> 10) & 1023u) * s;
    float f2 = (float)((w1 >> 20) & 1023u) * s;
    float a0 = 1.f - f0, a1 = 1.f - f1, a2 = 1.f - f2;
    float p00 = a0 * a1, p10 = f0 * a1, p01 = a0 * f1, p11 = f0 * f1;
    bb[0] = p00 * a2; bb[1] = p10 * a2; bb[2] = p01 * a2; bb[3] = p11 * a2;
    bb[4] = p00 * f2; bb[5] = p10 * f2; bb[6] = p01 * f2; bb[7] = p11 * f2;
}

__device__ __forceinline__ void spline_wf(const float* __restrict__ a3,
                                          int& wib, float fr[3]) {
    int k[3];
#pragma unroll
    for (int d = 0; d < 3; ++d) {
        float p = fminf(fmaxf(a3[d], 0.f), 1.f) * 4.f;
        float f0 = fminf(floorf(p), 3.f);
        k[d] = (int)f0;
        fr[d] = p - f0;
    }
    wib = k[0] * 25 + k[1] * 5 + k[2];
}

// ---------- preamble kernels ----------

// fast zero of counts+bcnt (replaces pathologically slow rocclr fillBuffer)
__global__ void zero_counts(int* __restrict__ p, int n) {
    int i = blockIdx.x * blockDim.x + threadIdx.x;
    if (i < n) p[i] = 0;
}

// x transform + dst histogram + block-aggregated wib histogram (counts/bcnt pre-zeroed)
__global__ __launch_bounds__(256) void hist_tr(
        const float* __restrict__ x, float* __restrict__ h,
        const int* __restrict__ dst, const float* __restrict__ attr,
        int* __restrict__ counts, int* __restrict__ bcnt, int N, int E) {
    __shared__ int lh[KTOT];
    const int tid = threadIdx.x;
    for (int i = tid; i < KTOT; i += 256) lh[i] = 0;
    __syncthreads();
    int i = blockIdx.x * 256 + tid;
    if (i < N) {
        float t = (x[i] - LOWER_CURV) / (UPPER_CURV - LOWER_CURV) * 20.0f - 10.0f;
        h[i] = fminf(fmaxf(t, -10.0f), 10.0f);
    }
    const int base = blockIdx.x * CHUNK;
#pragma unroll
    for (int k = 0; k < 8; ++k) {
        int e = base + tid + k * 256;
        if (e < E) {
            atomicAdd(&counts[dst[e]], 1);
            float a3[3] = {attr[e * 3], attr[e * 3 + 1], attr[e * 3 + 2]};
            int wib; float fr[3];
            spline_wf(a3, wib, fr);
            atomicAdd(&lh[wib], 1);
        }
    }
    __syncthreads();
    for (int j = tid; j < KTOT; j += 256) {
        int c = lh[j];
        if (c) atomicAdd(&bcnt[j], c);
    }
}

__global__ void scan_blocks(const int* __restrict__ counts, int* __restrict__ rowptr,
                            int* __restrict__ bsums, int n) {
    __shared__ int sh[256];
    int tid = threadIdx.x;
    int i = blockIdx.x * 256 + tid;
    int v = (i < n) ? counts[i] : 0;
    sh[tid] = v;
    __syncthreads();
    for (int off = 1; off < 256; off <<= 1) {
        int t = (tid >= off) ? sh[tid - off] : 0;
        __syncthreads();
        sh[tid] += t;
        __syncthreads();
    }
    if (i < n) rowptr[i] = sh[tid] - v;
    if (tid == 255) bsums[blockIdx.x] = sh[255];
}

// rowptr offset + cursor init; block 0 scans the 125 bucket counts PADDED TO 16
__global__ void add_offsets2(int* __restrict__ rowptr, const int* __restrict__ bsums,
                             int* __restrict__ cursor, const int* __restrict__ bcnt,
                             int* __restrict__ bases, int* __restrict__ bcursor,
                             int nb, int n, int E) {
    __shared__ int sh[256];
    __shared__ int sb[128];
    int tid = threadIdx.x;
    int v = (tid < nb) ? bsums[tid] : 0;
    sh[tid] = v;
    __syncthreads();
    for (int off = 1; off < 256; off <<= 1) {
        int t = (tid >= off) ? sh[tid - off] : 0;
        __syncthreads();
        sh[tid] += t;
        __syncthreads();
    }
    int boff = (blockIdx.x == 0) ? 0 : sh[blockIdx.x - 1];
    int i = blockIdx.x * 256 + tid;
    if (i < n) {
        int r = rowptr[i] + boff;
        rowptr[i] = r;
        cursor[i] = r;
    }
    if (i == 0) rowptr[n] = E;
    if (blockIdx.x == 0) {
        int cap = 0;
        if (tid < 128) {
            cap = (tid < KTOT) ? ((bcnt[tid] + 15) & ~15) : 0;
            sb[tid] = cap;
        }
        __syncthreads();
        for (int off = 1; off < 128; off <<= 1) {
            int t = (tid >= off && tid < 128) ? sb[tid - off] : 0;
            __syncthreads();
            if (tid < 128) sb[tid] += t;
            __syncthreads();
        }
        if (tid < KTOT) {
            int excl = sb[tid] - cap;
            bases[tid] = excl;
            bcursor[tid] = excl;
            if (tid == KTOT - 1) bases[KTOT] = excl + cap;
        }
    }
}

// GLOBAL bucket sort by wib (blocks < nchunk) + f16 weight-table prep
// (next nprep blocks; wh4 zero-padded to 16 cols) + pad fill (last KTOT blocks).
// Records 8B: w0 = src | wib<<18; w1 = q0|q1<<10|q2<<20.
__global__ __launch_bounds__(256) void scatter_prep(
        const int* __restrict__ src, const int* __restrict__ dst,
        const float* __restrict__ attr, int* __restrict__ cursor,
        int* __restrict__ bcursor, const int* __restrict__ bcnt,
        const int* __restrict__ bases,
        uint2* __restrict__ records, uint2* __restrict__ records_d,
        int* __restrict__ iperm, int E, int nchunk, int nprep,
        const float* __restrict__ W2, const float* __restrict__ W3,
        const float* __restrict__ W4, _Float16* __restrict__ wh2,
        _Float16* __restrict__ wh3, _Float16* __restrict__ wh4) {
    __shared__ int lh[KTOT], lbase[KTOT], lrank[KTOT];
    const int tid = threadIdx.x;

    if ((int)blockIdx.x >= nchunk + nprep) {
        // ---- pad fill: records in [bases[b]+bcnt[b], bases[b+1]) ----
        int b = (int)blockIdx.x - nchunk - nprep;
        int s = bases[b] + bcnt[b];
        int e = bases[b + 1];
        for (int i = s + tid; i < e; i += 256) {
            records[i] = make_uint2((unsigned)b << 18, 0u);
            iperm[i] = E;                // dump row
        }
        return;
    }
    if ((int)blockIdx.x >= nchunk) {
        // ---- weight prep: Wh[wi][(i>>3)][o][i&7] = W[wi][i][o] ----
        int idx = ((int)blockIdx.x - nchunk) * 256 + tid;   // < 80000
        if (idx >= 80000) return;
        if (idx < 16000) {
            // wh2: Cin=8, Cout=16
            int wi = idx / 128, q = idx % 128;
            int i = q / 16, o = q % 16;
            wh2[wi * 128 + o * 8 + i] = (_Float16)W2[idx];
        } else if (idx < 48000) {
            // wh3: Cin=16, Cout=16
            int r = idx - 16000;
            int wi = r / 256, q = r % 256;
            int i = q / 16, o = q % 16;
            wh3[wi * 256 + (i >> 3) * 128 + o * 8 + (i & 7)] = (_Float16)W3[r];
        } else {
            // wh4: Cin=16, Cout padded 8->16 (zeros for o>=8)
            int r = idx - 48000;                 // < 32000 = 125*16*16
            int wi = r / 256, q = r % 256;
            int i = q / 16, o = q % 16;
            float val = (o < 8) ? W4[(wi * 16 + i) * 8 + o] : 0.0f;
            wh4[wi * 256 + (i >> 3) * 128 + o * 8 + (i & 7)] = (_Float16)val;
        }
        return;
    }

    for (int i = tid; i < KTOT; i += 256) { lh[i] = 0; lrank[i] = 0; }
    __syncthreads();
    const int base = blockIdx.x * CHUNK;

    int wibs[8]; unsigned w1s[8];
#pragma unroll
    for (int k = 0; k < 8; ++k) {
        int e = base + tid + k * 256;
        wibs[k] = -1;
        if (e < E) {
            float a3[3] = {attr[e * 3], attr[e * 3 + 1], attr[e * 3 + 2]};
            int wib; float fr[3];
            spline_wf(a3, wib, fr);
            wibs[k] = wib;
            unsigned q0 = (unsigned)__float2int_rn(fr[0] * 1023.f);
            unsigned q1 = (unsigned)__float2int_rn(fr[1] * 1023.f);
            unsigned q2 = (unsigned)__float2int_rn(fr[2] * 1023.f);
            w1s[k] = q0 | (q1 << 10) | (q2 << 20);
            atomicAdd(&lh[wib], 1);
        }
    }
    __syncthreads();
    for (int i = tid; i < KTOT; i += 256) {
        int c = lh[i];
        lbase[i] = c ? atomicAdd(&bcursor[i], c) : 0;
    }
    __syncthreads();
#pragma unroll
    for (int k = 0; k < 8; ++k) {
        int e = base + tid + k * 256;
        if (e < E) {
            int w = wibs[k];
            int pos = lbase[w] + atomicAdd(&lrank[w], 1);
            uint2 rec = make_uint2((unsigned)src[e] | ((unsigned)w << 18), w1s[k]);
            records[pos] = rec;
            int p = atomicAdd(&cursor[dst[e]], 1);
            iperm[pos] = p;
            records_d[p] = rec;
        }
    }
}

// ---------- phase A (MFMA): 16-edge tiles, uniform wib ----------
// y[e,o] = sum_k A[e,k] B[k,o];  A[e,(t,i)] = bb[t,e]*x[e,i],
// B[(t,i),o] = W[wib+TAP[t]][i][o].  One mfma_f32_16x16x32_f16 per K=32 slice.
// CR = real output channels (y stride); B padded to 16 cols when CR<16.
template<int Cin, int CR>
__global__ __launch_bounds__(512) void edge_gemm_mfma(
        const uint2* __restrict__ records, const unsigned* __restrict__ xh,
        const _Float16* __restrict__ Wg, const int* __restrict__ iperm,
        _Float16* __restrict__ y, const int* __restrict__ epad_ptr) {
    constexpr int Cout = 16;
    constexpr int CC = Cin * Cout;
    constexpr int WH = KTOT * CC;
    constexpr int NM = Cin / 4;            // mfmas per tile (K=Cin*8 / 32)
    __shared__ __align__(16) _Float16 Wl[WH];
    for (int t = threadIdx.x; t < WH / 8; t += 512)
        ((uint4*)Wl)[t] = ((const uint4*)Wg)[t];
    __syncthreads();

    const int Ep = *epad_ptr;              // 16-aligned
    const int ntiles = Ep >> 4;
    const int lane = threadIdx.x & 63;
    const int o = lane & 15;               // edge-slot for A loads, out-col for B/D
    const int kb = lane >> 4;              // K-block 0..3
    const int chunk = (Cin == 16) ? (kb & 1) : 0;
    const int wid = blockIdx.x * 8 + (threadIdx.x >> 6);
    const int nwaves = gridDim.x * 8;
    constexpr int TAP[8] = {0, 25, 5, 30, 1, 26, 6, 31};

    for (int tile = wid; tile < ntiles; tile += nwaves) {
        const int tb = tile << 4;
        uint2 rec = records[tb + o];
        const int wib = (int)(((unsigned)__builtin_amdgcn_readfirstlane((int)rec.x)) >> 18);
        float bb[8];
        unpack_bb10(rec.y, bb);
        const unsigned sn = rec.x & 0x3FFFFu;
        uint4 xq = *(const uint4*)(xh + (size_t)sn * (Cin / 2) + chunk * 4);
        h2 xv[4];
        xv[0] = __builtin_bit_cast(h2, xq.x);
        xv[1] = __builtin_bit_cast(h2, xq.y);
        xv[2] = __builtin_bit_cast(h2, xq.z);
        xv[3] = __builtin_bit_cast(h2, xq.w);

        f32x4 acc = {0.f, 0.f, 0.f, 0.f};
#pragma unroll
        for (int m = 0; m < NM; ++m) {
            const int t = (Cin == 16) ? (2 * m + (kb >> 1)) : (4 * m + kb);
            const int wi = wib + TAP[t];
            _Float16 sh = (_Float16)bb[t];
            h2 ss; ss[0] = sh; ss[1] = sh;
            union { h8_t v; h2 h[4]; uint4 q; } A, B;
            A.h[0] = xv[0] * ss; A.h[1] = xv[1] * ss;
            A.h[2] = xv[2] * ss; A.h[3] = xv[3] * ss;
            B.q = *(const uint4*)&Wl[wi * CC + chunk * (8 * Cout) + o * 8];
            acc = __builtin_amdgcn_mfma_f32_16x16x32_f16(A.v, B.v, acc, 0, 0, 0);
        }
        // D: col = lane&15, row = kb*4 + r  (edge index within tile)
        if (CR == 16 || o < CR) {
#pragma unroll
            for (int r = 0; r < 4; ++r) {
                int dp = iperm[tb + kb * 4 + r];
                y[(size_t)dp * CR + o] = (_Float16)acc[r];
            }
        }
    }
}

// ---------- phase B: sequential y reduce + root + ELU; writes f32 + packed f16 ----------
template<int Cin, int Cout>
__global__ void node_reduce(const int* __restrict__ rowptr,
                            const unsigned* __restrict__ yu,
                            const float* __restrict__ x,
                            const float* __restrict__ root,
                            const float* __restrict__ bias,
                            float* __restrict__ out, unsigned* __restrict__ xh,
                            int N) {
    constexpr int C2 = Cout / 2;
    int t = blockIdx.x * blockDim.x + threadIdx.x;
    int v = t / C2, o2 = t % C2;
    if (v >= N) return;
    int beg = rowptr[v], end = rowptr[v + 1];
    float a0 = 0.f, a1 = 0.f;
    for (int p = beg; p < end; ++p) {
        h2 hh = __builtin_bit_cast(h2, yu[(size_t)p * C2 + o2]);
        a0 += (float)hh[0];
        a1 += (float)hh[1];
    }
    const int o = 2 * o2;
    a0 += bias[o]; a1 += bias[o + 1];
#pragma unroll
    for (int i = 0; i < Cin; ++i) {
        float xv = x[(size_t)v * Cin + i];
        a0 = fmaf(xv, root[i * Cout + o], a0);
        a1 = fmaf(xv, root[i * Cout + o + 1], a1);
    }
    a0 = a0 > 0.f ? a0 : expm1f(a0);
    a1 = a1 > 0.f ? a1 : expm1f(a1);
    ((float2*)out)[(size_t)v * C2 + o2] = make_float2(a0, a1);
    xh[(size_t)v * C2 + o2] = pack_u32(a0, a1);
}

// ---------- fused small layers (records_d in dst-CSR order: contiguous reads) ----------

__global__ __launch_bounds__(512) void agg_l1(
        const int* __restrict__ rowptr, const uint2* __restrict__ records_d,
        const float* __restrict__ x, const float* __restrict__ W,
        const float* __restrict__ root, const float* __restrict__ bias,
        float* __restrict__ out, unsigned* __restrict__ xh2,
        int N, int totalWaves) {
    const int lane = threadIdx.x & 63;
    const int o = lane & 7;
    const int slot = lane >> 3;
    const int wid = blockIdx.x * 8 + (threadIdx.x >> 6);
    constexpr int TAP[8] = {0, 25, 5, 30, 1, 26, 6, 31};

    for (int v = wid; v < N; v += totalWaves) {
        const int beg = rowptr[v], end = rowptr[v + 1];
        float acc = 0.0f;
        for (int p0 = beg; p0 < end; p0 += 8) {
            const int p = p0 + slot;
            float xv = 0.f, bb[8];
            int wib = 0;
#pragma unroll
            for (int t = 0; t < 8; ++t) bb[t] = 0.f;
            if (p < end) {
                uint2 rec = records_d[p];
                unpack_bb10(rec.y, bb);
                wib = (int)(rec.x >> 18);
                xv = x[rec.x & 0x3FFFFu];
            }
#pragma unroll
            for (int t = 0; t < 8; ++t)
                acc = fmaf(bb[t] * xv, __ldg(&W[(wib + TAP[t]) * 8 + o]), acc);
        }
#pragma unroll
        for (int m = 8; m < 64; m <<= 1) acc += __shfl_xor(acc, m);
        if (slot == 0) {
            float z = acc + bias[o] + x[v] * root[o];
            z = z > 0.0f ? z : expm1f(z);
            out[(size_t)v * 8 + o] = z;
            float zp = __shfl_xor(z, 1);
            if ((o & 1) == 0) xh2[(size_t)v * 4 + (o >> 1)] = pack_u32(z, zp);
        }
    }
}

__global__ __launch_bounds__(512) void agg_l5(
        const int* __restrict__ rowptr, const uint2* __restrict__ records_d,
        const float* __restrict__ x, const float* __restrict__ W,
        const float* __restrict__ root, const float* __restrict__ bias,
        float* __restrict__ out, int N, int totalWaves) {
    const int lane = threadIdx.x & 63;
    const int i = lane & 7;
    const int slot = lane >> 3;
    const int wid = blockIdx.x * 8 + (threadIdx.x >> 6);
    constexpr int TAP[8] = {0, 25, 5, 30, 1, 26, 6, 31};

    for (int v = wid; v < N; v += totalWaves) {
        const int beg = rowptr[v], end = rowptr[v + 1];
        float acc = 0.0f;
        for (int p0 = beg; p0 < end; p0 += 8) {
            const int p = p0 + slot;
            float xi = 0.f, bb[8];
            int wib = 0;
#pragma unroll
            for (int t = 0; t < 8; ++t) bb[t] = 0.f;
            if (p < end) {
                uint2 rec = records_d[p];
                unpack_bb10(rec.y, bb);
                wib = (int)(rec.x >> 18);
                xi = x[(size_t)(rec.x & 0x3FFFFu) * 8 + i];
            }
#pragma unroll
            for (int t = 0; t < 8; ++t)
                acc = fmaf(bb[t] * xi, __ldg(&W[(wib + TAP[t]) * 8 + i]), acc);
        }
        if (slot == 0) acc = fmaf(x[(size_t)v * 8 + i], root[i], acc);
#pragma unroll
        for (int m = 1; m < 64; m <<= 1) acc += __shfl_xor(acc, m);
        if (lane == 0) {
            float z = acc + bias[0];
            out[v] = z > 0.0f ? z : expm1f(z);
        }
    }
}

// ---------- host ----------

static inline char* align256(char* p) {
    return (char*)(((uintptr_t)p + 255) & ~(uintptr_t)255);
}

extern "C" void kernel_launch(void* const* d_in, const int* in_sizes, int n_in,
                              void* d_out, int out_size, void* d_ws, size_t ws_size,
                              hipStream_t stream) {
    const float* x    = (const float*)d_in[0];
    const int*   ei   = (const int*)d_in[1];
    const float* attr = (const float*)d_in[2];
    const float* w[5]    = {(const float*)d_in[3],  (const float*)d_in[6],
                            (const float*)d_in[9],  (const float*)d_in[12],
                            (const float*)d_in[15]};
    const float* root[5] = {(const float*)d_in[4],  (const float*)d_in[7],
                            (const float*)d_in[10], (const float*)d_in[13],
                            (const float*)d_in[16]};
    const float* bias[5] = {(const float*)d_in[5],  (const float*)d_in[8],
                            (const float*)d_in[11], (const float*)d_in[14],
                            (const float*)d_in[17]};

    const int N = in_sizes[0];
    const int E = in_sizes[1] / 2;
    const int* src = ei;
    const int* dst = ei + E;
    const int EPCAP = E + 2048;     // capacity incl. bucket pads (<=125*15)

    char* ws = (char*)d_ws;
    float* bufA      = (float*)ws;    ws = align256(ws + (size_t)N * 16 * 4);
    float* bufB      = (float*)ws;    ws = align256(ws + (size_t)N * 16 * 4);
    int*   counts    = (int*)ws;      ws = align256(ws + (size_t)(N + 128) * 4);
    int*   bcnt      = counts + N;    // zeroed together with counts
    int*   cursor    = (int*)ws;      ws = align256(ws + (size_t)N * 4);
    int*   rowptr    = (int*)ws;      ws = align256(ws + (size_t)(N + 1) * 4);
    int*   bsums     = (int*)ws;      ws = align256(ws + 256 * 4);
    int*   bases     = (int*)ws;      ws = align256(ws + 128 * 4);
    int*   bcursor   = (int*)ws;      ws = align256(ws + 128 * 4);
    uint2* records   = (uint2*)ws;    ws = align256(ws + (size_t)EPCAP * 8);
    uint2* records_d = (uint2*)ws;    ws = align256(ws + (size_t)E * 8);
    int*   iperm     = (int*)ws;      ws = align256(ws + (size_t)EPCAP * 4);
    _Float16* y      = (_Float16*)ws; ws = align256(ws + (size_t)(E + 16) * 16 * 2);
    unsigned* xhA    = (unsigned*)ws; ws = align256(ws + (size_t)N * 8 * 4);
    unsigned* xhB    = (unsigned*)ws; ws = align256(ws + (size_t)N * 8 * 4);
    _Float16* wh2    = (_Float16*)ws; ws = align256(ws + (size_t)KTOT * 8 * 16 * 2);
    _Float16* wh3    = (_Float16*)ws; ws = align256(ws + (size_t)KTOT * 16 * 16 * 2);
    _Float16* wh4    = (_Float16*)ws; ws = align256(ws + (size_t)KTOT * 16 * 16 * 2); // padded

    const int B = 256;
    const int nb = cdiv(N, 256);
    const int nchunk = cdiv(E, CHUNK);
    const int nprep = cdiv(80000, 256);
    const int* epad = bases + KTOT;
    const unsigned* yu = (const unsigned*)y;

    zero_counts<<<cdiv(N + 128, B), B, 0, stream>>>(counts, N + 128);
    hist_tr<<<nchunk, 256, 0, stream>>>(x, bufA, dst, attr, counts, bcnt, N, E);
    scan_blocks<<<nb, 256, 0, stream>>>(counts, rowptr, bsums, N);
    add_offsets2<<<nb, 256, 0, stream>>>(rowptr, bsums, cursor, bcnt, bases,
                                         bcursor, nb, N, E);
    scatter_prep<<<nchunk + nprep + KTOT, 256, 0, stream>>>(
        src, dst, attr, cursor, bcursor, bcnt, bases,
        records, records_d, iperm, E, nchunk, nprep,
        w[1], w[2], w[3], wh2, wh3, wh4);

    const int GB = 512, TW = GB * 8;

    // L1 (1->8), fused; writes f32 out + f16 xhA
    agg_l1<<<GB, 512, 0, stream>>>(rowptr, records_d, bufA, w[0],
                                   root[0], bias[0], bufB, xhA, N, TW);
    // L2 (8->16), MFMA
    edge_gemm_mfma<8, 16><<<GB, 512, 0, stream>>>(records, xhA, wh2, iperm, y, epad);
    node_reduce<8, 16><<<cdiv(N * 8, B), B, 0, stream>>>(rowptr, yu, bufB,
                                                         root[1], bias[1], bufA, xhB, N);
    // L3 (16->16), MFMA
    edge_gemm_mfma<16, 16><<<GB, 512, 0, stream>>>(records, xhB, wh3, iperm, y, epad);
    node_reduce<16, 16><<<cdiv(N * 8, B), B, 0, stream>>>(rowptr, yu, bufA,
                                                          root[2], bias[2], bufB, xhA, N);
    // L4 (16->8), MFMA with padded B (8 real cols)
    edge_gemm_mfma<16, 8><<<GB, 512, 0, stream>>>(records, xhA, wh4, iperm, y, epad);
    node_reduce<16, 8><<<cdiv(N * 4, B), B, 0, stream>>>(rowptr, yu, bufB,
                                                         root[3], bias[3], bufA, xhB, N);
    // L5 (8->1), fused
    agg_l5<<<GB, 512, 0, stream>>>(rowptr, records_d, bufA, w[4],
                                   root[4], bias[4], (float*)d_out, N, TW);
}

// Round 18
// 154.700 us; speedup vs baseline: 1.4647x; 1.1342x over previous
//
#include <hip/hip_runtime.h>
#include <math.h>

#define KSIZE 5
#define KTOT 125
#define CHUNK 2048

static constexpr float LOWER_CURV = -0.22703196f;
static constexpr float UPPER_CURV = 0.36853024f;

typedef _Float16 h2 __attribute__((ext_vector_type(2)));
typedef _Float16 h8_t __attribute__((ext_vector_type(8)));
typedef float f32x4 __attribute__((ext_vector_type(4)));

__device__ __forceinline__ unsigned pack_u32(float a, float b) {
    return __builtin_bit_cast(unsigned, __builtin_amdgcn_cvt_pkrtz(a, b));
}
__device__ __forceinline__ float fdot2f(h2 a, h2 b, float c) {
#if __has_builtin(__builtin_amdgcn_fdot2)
    return __builtin_amdgcn_fdot2(a, b, c, false);
#else
    return c + (float)a[0] * (float)b[0] + (float)a[1] * (float)b[1];
#endif
}

__host__ __device__ static inline int cdiv(int a, int b) { return (a + b - 1) / b; }

// basis from 10-bit quantized fractions; bb[t] matches TAP[t]
__device__ __forceinline__ void unpack_bb10(unsigned w1, float bb[8]) {
    const float s = 1.0f / 1023.0f;
    float f0 = (float)(w1 & 1023u) * s;
    float f1 = (float)((w1 >> 10) & 1023u) * s;
    float f2 = (float)((w1 >> 20) & 1023u) * s;
    float a0 = 1.f - f0, a1 = 1.f - f1, a2 = 1.f - f2;
    float p00 = a0 * a1, p10 = f0 * a1, p01 = a0 * f1, p11 = f0 * f1;
    bb[0] = p00 * a2; bb[1] = p10 * a2; bb[2] = p01 * a2; bb[3] = p11 * a2;
    bb[4] = p00 * f2; bb[5] = p10 * f2; bb[6] = p01 * f2; bb[7] = p11 * f2;
}

__device__ __forceinline__ void spline_wf(const float* __restrict__ a3,
                                          int& wib, float fr[3]) {
    int k[3];
#pragma unroll
    for (int d = 0; d < 3; ++d) {
        float p = fminf(fmaxf(a3[d], 0.f), 1.f) * 4.f;
        float f0 = fminf(floorf(p), 3.f);
        k[d] = (int)f0;
        fr[d] = p - f0;
    }
    wib = k[0] * 25 + k[1] * 5 + k[2];
}

// ---------- preamble kernels ----------

__global__ void zero_counts(int* __restrict__ p, int n) {
    int i = blockIdx.x * blockDim.x + threadIdx.x;
    if (i < n) p[i] = 0;
}

// x transform + dst histogram + block-aggregated wib histogram (counts/bcnt pre-zeroed)
__global__ __launch_bounds__(256) void hist_tr(
        const float* __restrict__ x, float* __restrict__ h,
        const int* __restrict__ dst, const float* __restrict__ attr,
        int* __restrict__ counts, int* __restrict__ bcnt, int N, int E) {
    __shared__ int lh[KTOT];
    const int tid = threadIdx.x;
    for (int i = tid; i < KTOT; i += 256) lh[i] = 0;
    __syncthreads();
    int i = blockIdx.x * 256 + tid;
    if (i < N) {
        float t = (x[i] - LOWER_CURV) / (UPPER_CURV - LOWER_CURV) * 20.0f - 10.0f;
        h[i] = fminf(fmaxf(t, -10.0f), 10.0f);
    }
    const int base = blockIdx.x * CHUNK;
#pragma unroll
    for (int k = 0; k < 8; ++k) {
        int e = base + tid + k * 256;
        if (e < E) {
            atomicAdd(&counts[dst[e]], 1);
            float a3[3] = {attr[e * 3], attr[e * 3 + 1], attr[e * 3 + 2]};
            int wib; float fr[3];
            spline_wf(a3, wib, fr);
            atomicAdd(&lh[wib], 1);
        }
    }
    __syncthreads();
    for (int j = tid; j < KTOT; j += 256) {
        int c = lh[j];
        if (c) atomicAdd(&bcnt[j], c);
    }
}

__global__ void scan_blocks(const int* __restrict__ counts, int* __restrict__ rowptr,
                            int* __restrict__ bsums, int n) {
    __shared__ int sh[256];
    int tid = threadIdx.x;
    int i = blockIdx.x * 256 + tid;
    int v = (i < n) ? counts[i] : 0;
    sh[tid] = v;
    __syncthreads();
    for (int off = 1; off < 256; off <<= 1) {
        int t = (tid >= off) ? sh[tid - off] : 0;
        __syncthreads();
        sh[tid] += t;
        __syncthreads();
    }
    if (i < n) rowptr[i] = sh[tid] - v;
    if (tid == 255) bsums[blockIdx.x] = sh[255];
}

// rowptr offset + cursor init; block 0 scans the 125 bucket counts PADDED TO 16
__global__ void add_offsets2(int* __restrict__ rowptr, const int* __restrict__ bsums,
                             int* __restrict__ cursor, const int* __restrict__ bcnt,
                             int* __restrict__ bases, int* __restrict__ bcursor,
                             int nb, int n, int E) {
    __shared__ int sh[256];
    __shared__ int sb[128];
    int tid = threadIdx.x;
    int v = (tid < nb) ? bsums[tid] : 0;
    sh[tid] = v;
    __syncthreads();
    for (int off = 1; off < 256; off <<= 1) {
        int t = (tid >= off) ? sh[tid - off] : 0;
        __syncthreads();
        sh[tid] += t;
        __syncthreads();
    }
    int boff = (blockIdx.x == 0) ? 0 : sh[blockIdx.x - 1];
    int i = blockIdx.x * 256 + tid;
    if (i < n) {
        int r = rowptr[i] + boff;
        rowptr[i] = r;
        cursor[i] = r;
    }
    if (i == 0) rowptr[n] = E;
    if (blockIdx.x == 0) {
        int cap = 0;
        if (tid < 128) {
            cap = (tid < KTOT) ? ((bcnt[tid] + 15) & ~15) : 0;
            sb[tid] = cap;
        }
        __syncthreads();
        for (int off = 1; off < 128; off <<= 1) {
            int t = (tid >= off && tid < 128) ? sb[tid - off] : 0;
            __syncthreads();
            if (tid < 128) sb[tid] += t;
            __syncthreads();
        }
        if (tid < KTOT) {
            int excl = sb[tid] - cap;
            bases[tid] = excl;
            bcursor[tid] = excl;
            if (tid == KTOT - 1) bases[KTOT] = excl + cap;
        }
    }
}

// GLOBAL bucket sort by wib (blocks < nchunk) + f16 weight-table prep
// (next nprep blocks; wh4 zero-padded to 16 cols) + pad fill (last KTOT blocks).
// Records 8B: w0 = src | wib<<18; w1 = q0|q1<<10|q2<<20.  (no records_d)
__global__ __launch_bounds__(256) void scatter_prep(
        const int* __restrict__ src, const int* __restrict__ dst,
        const float* __restrict__ attr, int* __restrict__ cursor,
        int* __restrict__ bcursor, const int* __restrict__ bcnt,
        const int* __restrict__ bases,
        uint2* __restrict__ records, int* __restrict__ iperm,
        int E, int nchunk, int nprep,
        const float* __restrict__ W2, const float* __restrict__ W3,
        const float* __restrict__ W4, _Float16* __restrict__ wh2,
        _Float16* __restrict__ wh3, _Float16* __restrict__ wh4) {
    __shared__ int lh[KTOT], lbase[KTOT], lrank[KTOT];
    const int tid = threadIdx.x;

    if ((int)blockIdx.x >= nchunk + nprep) {
        // ---- pad fill ----
        int b = (int)blockIdx.x - nchunk - nprep;
        int s = bases[b] + bcnt[b];
        int e = bases[b + 1];
        for (int i = s + tid; i < e; i += 256) {
            records[i] = make_uint2((unsigned)b << 18, 0u);
            iperm[i] = E;                // dump row
        }
        return;
    }
    if ((int)blockIdx.x >= nchunk) {
        int idx = ((int)blockIdx.x - nchunk) * 256 + tid;   // < 80000
        if (idx >= 80000) return;
        if (idx < 16000) {
            int wi = idx / 128, q = idx % 128;
            int i = q / 16, o = q % 16;
            wh2[wi * 128 + o * 8 + i] = (_Float16)W2[idx];
        } else if (idx < 48000) {
            int r = idx - 16000;
            int wi = r / 256, q = r % 256;
            int i = q / 16, o = q % 16;
            wh3[wi * 256 + (i >> 3) * 128 + o * 8 + (i & 7)] = (_Float16)W3[r];
        } else {
            int r = idx - 48000;                 // < 32000
            int wi = r / 256, q = r % 256;
            int i = q / 16, o = q % 16;
            float val = (o < 8) ? W4[(wi * 16 + i) * 8 + o] : 0.0f;
            wh4[wi * 256 + (i >> 3) * 128 + o * 8 + (i & 7)] = (_Float16)val;
        }
        return;
    }

    for (int i = tid; i < KTOT; i += 256) { lh[i] = 0; lrank[i] = 0; }
    __syncthreads();
    const int base = blockIdx.x * CHUNK;

    int wibs[8]; unsigned w1s[8];
#pragma unroll
    for (int k = 0; k < 8; ++k) {
        int e = base + tid + k * 256;
        wibs[k] = -1;
        if (e < E) {
            float a3[3] = {attr[e * 3], attr[e * 3 + 1], attr[e * 3 + 2]};
            int wib; float fr[3];
            spline_wf(a3, wib, fr);
            wibs[k] = wib;
            unsigned q0 = (unsigned)__float2int_rn(fr[0] * 1023.f);
            unsigned q1 = (unsigned)__float2int_rn(fr[1] * 1023.f);
            unsigned q2 = (unsigned)__float2int_rn(fr[2] * 1023.f);
            w1s[k] = q0 | (q1 << 10) | (q2 << 20);
            atomicAdd(&lh[wib], 1);
        }
    }
    __syncthreads();
    for (int i = tid; i < KTOT; i += 256) {
        int c = lh[i];
        lbase[i] = c ? atomicAdd(&bcursor[i], c) : 0;
    }
    __syncthreads();
#pragma unroll
    for (int k = 0; k < 8; ++k) {
        int e = base + tid + k * 256;
        if (e < E) {
            int w = wibs[k];
            int pos = lbase[w] + atomicAdd(&lrank[w], 1);
            records[pos] = make_uint2((unsigned)src[e] | ((unsigned)w << 18), w1s[k]);
            iperm[pos] = atomicAdd(&cursor[dst[e]], 1);
        }
    }
}

// ---------- L1 edge kernel: lane=edge, broadcast f32 weights, y1[e][8] f16 ----------
__global__ __launch_bounds__(512) void l1_edge(
        const uint2* __restrict__ records, const float* __restrict__ h,
        const float* __restrict__ W1,      // [125][8] f32
        const int* __restrict__ iperm, _Float16* __restrict__ y,
        const int* __restrict__ epad_ptr) {
    __shared__ float Wl[KTOT * 8];
    for (int i = threadIdx.x; i < KTOT * 8; i += 512) Wl[i] = W1[i];
    __syncthreads();
    const int Ep = *epad_ptr;
    const int stride = gridDim.x * 512;
    constexpr int TAP[8] = {0, 25, 5, 30, 1, 26, 6, 31};
    for (int idx = blockIdx.x * 512 + threadIdx.x; idx < Ep; idx += stride) {
        uint2 rec = records[idx];
        float bb[8];
        unpack_bb10(rec.y, bb);
        const int wib = (int)(rec.x >> 18);
        float xv = h[rec.x & 0x3FFFFu];
        float s[8];
#pragma unroll
        for (int o = 0; o < 8; ++o) s[o] = 0.f;
#pragma unroll
        for (int t = 0; t < 8; ++t) {
            const float* wp = &Wl[(wib + TAP[t]) * 8];
#pragma unroll
            for (int o = 0; o < 8; ++o) s[o] = fmaf(bb[t], wp[o], s[o]);
        }
        uint4 pk;
        pk.x = pack_u32(xv * s[0], xv * s[1]);
        pk.y = pack_u32(xv * s[2], xv * s[3]);
        pk.z = pack_u32(xv * s[4], xv * s[5]);
        pk.w = pack_u32(xv * s[6], xv * s[7]);
        int dp = iperm[idx];
        *(uint4*)&y[(size_t)dp * 8] = pk;
    }
}

// ---------- L5 edge kernel: lane=edge, f16 x, broadcast weights, scalar f32 y5 ----------
__global__ __launch_bounds__(512) void l5_edge(
        const uint2* __restrict__ records, const unsigned* __restrict__ xh,
        const float* __restrict__ W5,      // [125][8] f32
        const int* __restrict__ iperm, float* __restrict__ y5,
        const int* __restrict__ epad_ptr) {
    __shared__ h2 Wl[KTOT * 4];
    for (int i = threadIdx.x; i < KTOT * 4; i += 512)
        Wl[i] = __builtin_bit_cast(h2, pack_u32(W5[2 * i], W5[2 * i + 1]));
    __syncthreads();
    const int Ep = *epad_ptr;
    const int stride = gridDim.x * 512;
    constexpr int TAP[8] = {0, 25, 5, 30, 1, 26, 6, 31};
    for (int idx = blockIdx.x * 512 + threadIdx.x; idx < Ep; idx += stride) {
        uint2 rec = records[idx];
        float bb[8];
        unpack_bb10(rec.y, bb);
        const int wib = (int)(rec.x >> 18);
        uint4 xq = *(const uint4*)(xh + (size_t)(rec.x & 0x3FFFFu) * 4);
        h2 hx[4];
        hx[0] = __builtin_bit_cast(h2, xq.x);
        hx[1] = __builtin_bit_cast(h2, xq.y);
        hx[2] = __builtin_bit_cast(h2, xq.z);
        hx[3] = __builtin_bit_cast(h2, xq.w);
        float acc = 0.f;
#pragma unroll
        for (int t = 0; t < 8; ++t) {
            const h2* wp = &Wl[(wib + TAP[t]) * 4];
            float dot = 0.f;
            dot = fdot2f(hx[0], wp[0], dot);
            dot = fdot2f(hx[1], wp[1], dot);
            dot = fdot2f(hx[2], wp[2], dot);
            dot = fdot2f(hx[3], wp[3], dot);
            acc = fmaf(bb[t], dot, acc);
        }
        y5[iperm[idx]] = acc;
    }
}

// final node reduce for L5: sum scalars + root + bias + ELU
__global__ void node_fin5(const int* __restrict__ rowptr, const float* __restrict__ y5,
                          const float* __restrict__ x,   // [N][8] f32
                          const float* __restrict__ root, const float* __restrict__ bias,
                          float* __restrict__ out, int N) {
    int v = blockIdx.x * blockDim.x + threadIdx.x;
    if (v >= N) return;
    int beg = rowptr[v], end = rowptr[v + 1];
    float acc = bias[0];
    for (int p = beg; p < end; ++p) acc += y5[p];
#pragma unroll
    for (int i = 0; i < 8; ++i)
        acc = fmaf(x[(size_t)v * 8 + i], root[i], acc);
    out[v] = acc > 0.f ? acc : expm1f(acc);
}

// ---------- phase A (MFMA): 16-edge tiles, uniform wib ----------
template<int Cin, int CR>
__global__ __launch_bounds__(512) void edge_gemm_mfma(
        const uint2* __restrict__ records, const unsigned* __restrict__ xh,
        const _Float16* __restrict__ Wg, const int* __restrict__ iperm,
        _Float16* __restrict__ y, const int* __restrict__ epad_ptr) {
    constexpr int Cout = 16;
    constexpr int CC = Cin * Cout;
    constexpr int WH = KTOT * CC;
    constexpr int NM = Cin / 4;
    __shared__ __align__(16) _Float16 Wl[WH];
    for (int t = threadIdx.x; t < WH / 8; t += 512)
        ((uint4*)Wl)[t] = ((const uint4*)Wg)[t];
    __syncthreads();

    const int Ep = *epad_ptr;
    const int ntiles = Ep >> 4;
    const int lane = threadIdx.x & 63;
    const int o = lane & 15;
    const int kb = lane >> 4;
    const int chunk = (Cin == 16) ? (kb & 1) : 0;
    const int wid = blockIdx.x * 8 + (threadIdx.x >> 6);
    const int nwaves = gridDim.x * 8;
    constexpr int TAP[8] = {0, 25, 5, 30, 1, 26, 6, 31};

    for (int tile = wid; tile < ntiles; tile += nwaves) {
        const int tb = tile << 4;
        uint2 rec = records[tb + o];
        const int wib = (int)(((unsigned)__builtin_amdgcn_readfirstlane((int)rec.x)) >> 18);
        float bb[8];
        unpack_bb10(rec.y, bb);
        const unsigned sn = rec.x & 0x3FFFFu;
        uint4 xq = *(const uint4*)(xh + (size_t)sn * (Cin / 2) + chunk * 4);
        h2 xv[4];
        xv[0] = __builtin_bit_cast(h2, xq.x);
        xv[1] = __builtin_bit_cast(h2, xq.y);
        xv[2] = __builtin_bit_cast(h2, xq.z);
        xv[3] = __builtin_bit_cast(h2, xq.w);

        f32x4 acc = {0.f, 0.f, 0.f, 0.f};
#pragma unroll
        for (int m = 0; m < NM; ++m) {
            const int t = (Cin == 16) ? (2 * m + (kb >> 1)) : (4 * m + kb);
            const int wi = wib + TAP[t];
            _Float16 sh = (_Float16)bb[t];
            h2 ss; ss[0] = sh; ss[1] = sh;
            union { h8_t v; h2 h[4]; uint4 q; } A, B;
            A.h[0] = xv[0] * ss; A.h[1] = xv[1] * ss;
            A.h[2] = xv[2] * ss; A.h[3] = xv[3] * ss;
            B.q = *(const uint4*)&Wl[wi * CC + chunk * (8 * Cout) + o * 8];
            acc = __builtin_amdgcn_mfma_f32_16x16x32_f16(A.v, B.v, acc, 0, 0, 0);
        }
        if (CR == 16 || o < CR) {
#pragma unroll
            for (int r = 0; r < 4; ++r) {
                int dp = iperm[tb + kb * 4 + r];
                y[(size_t)dp * CR + o] = (_Float16)acc[r];
            }
        }
    }
}

// ---------- phase B: sequential y reduce + root + ELU; writes f32 + packed f16 ----------
template<int Cin, int Cout>
__global__ void node_reduce(const int* __restrict__ rowptr,
                            const unsigned* __restrict__ yu,
                            const float* __restrict__ x,
                            const float* __restrict__ root,
                            const float* __restrict__ bias,
                            float* __restrict__ out, unsigned* __restrict__ xh,
                            int N) {
    constexpr int C2 = Cout / 2;
    int t = blockIdx.x * blockDim.x + threadIdx.x;
    int v = t / C2, o2 = t % C2;
    if (v >= N) return;
    int beg = rowptr[v], end = rowptr[v + 1];
    float a0 = 0.f, a1 = 0.f;
    for (int p = beg; p < end; ++p) {
        h2 hh = __builtin_bit_cast(h2, yu[(size_t)p * C2 + o2]);
        a0 += (float)hh[0];
        a1 += (float)hh[1];
    }
    const int o = 2 * o2;
    a0 += bias[o]; a1 += bias[o + 1];
#pragma unroll
    for (int i = 0; i < Cin; ++i) {
        float xv = x[(size_t)v * Cin + i];
        a0 = fmaf(xv, root[i * Cout + o], a0);
        a1 = fmaf(xv, root[i * Cout + o + 1], a1);
    }
    a0 = a0 > 0.f ? a0 : expm1f(a0);
    a1 = a1 > 0.f ? a1 : expm1f(a1);
    ((float2*)out)[(size_t)v * C2 + o2] = make_float2(a0, a1);
    xh[(size_t)v * C2 + o2] = pack_u32(a0, a1);
}

// ---------- host ----------

static inline char* align256(char* p) {
    return (char*)(((uintptr_t)p + 255) & ~(uintptr_t)255);
}

extern "C" void kernel_launch(void* const* d_in, const int* in_sizes, int n_in,
                              void* d_out, int out_size, void* d_ws, size_t ws_size,
                              hipStream_t stream) {
    const float* x    = (const float*)d_in[0];
    const int*   ei   = (const int*)d_in[1];
    const float* attr = (const float*)d_in[2];
    const float* w[5]    = {(const float*)d_in[3],  (const float*)d_in[6],
                            (const float*)d_in[9],  (const float*)d_in[12],
                            (const float*)d_in[15]};
    const float* root[5] = {(const float*)d_in[4],  (const float*)d_in[7],
                            (const float*)d_in[10], (const float*)d_in[13],
                            (const float*)d_in[16]};
    const float* bias[5] = {(const float*)d_in[5],  (const float*)d_in[8],
                            (const float*)d_in[11], (const float*)d_in[14],
                            (const float*)d_in[17]};

    const int N = in_sizes[0];
    const int E = in_sizes[1] / 2;
    const int* src = ei;
    const int* dst = ei + E;
    const int EPCAP = E + 2048;

    char* ws = (char*)d_ws;
    float* bufA      = (float*)ws;    ws = align256(ws + (size_t)N * 16 * 4);
    float* bufB      = (float*)ws;    ws = align256(ws + (size_t)N * 16 * 4);
    int*   counts    = (int*)ws;      ws = align256(ws + (size_t)(N + 128) * 4);
    int*   bcnt      = counts + N;
    int*   cursor    = (int*)ws;      ws = align256(ws + (size_t)N * 4);
    int*   rowptr    = (int*)ws;      ws = align256(ws + (size_t)(N + 1) * 4);
    int*   bsums     = (int*)ws;      ws = align256(ws + 256 * 4);
    int*   bases     = (int*)ws;      ws = align256(ws + 128 * 4);
    int*   bcursor   = (int*)ws;      ws = align256(ws + 128 * 4);
    uint2* records   = (uint2*)ws;    ws = align256(ws + (size_t)EPCAP * 8);
    int*   iperm     = (int*)ws;      ws = align256(ws + (size_t)EPCAP * 4);
    _Float16* y      = (_Float16*)ws; ws = align256(ws + (size_t)(E + 16) * 16 * 2);
    unsigned* xhA    = (unsigned*)ws; ws = align256(ws + (size_t)N * 8 * 4);
    unsigned* xhB    = (unsigned*)ws; ws = align256(ws + (size_t)N * 8 * 4);
    _Float16* wh2    = (_Float16*)ws; ws = align256(ws + (size_t)KTOT * 8 * 16 * 2);
    _Float16* wh3    = (_Float16*)ws; ws = align256(ws + (size_t)KTOT * 16 * 16 * 2);
    _Float16* wh4    = (_Float16*)ws; ws = align256(ws + (size_t)KTOT * 16 * 16 * 2);

    const int B = 256;
    const int nb = cdiv(N, 256);
    const int nchunk = cdiv(E, CHUNK);
    const int nprep = cdiv(80000, 256);
    const int* epad = bases + KTOT;
    const unsigned* yu = (const unsigned*)y;
    float* y5 = (float*)y;

    zero_counts<<<cdiv(N + 128, B), B, 0, stream>>>(counts, N + 128);
    hist_tr<<<nchunk, 256, 0, stream>>>(x, bufA, dst, attr, counts, bcnt, N, E);
    scan_blocks<<<nb, 256, 0, stream>>>(counts, rowptr, bsums, N);
    add_offsets2<<<nb, 256, 0, stream>>>(rowptr, bsums, cursor, bcnt, bases,
                                         bcursor, nb, N, E);
    scatter_prep<<<nchunk + nprep + KTOT, 256, 0, stream>>>(
        src, dst, attr, cursor, bcursor, bcnt, bases,
        records, iperm, E, nchunk, nprep,
        w[1], w[2], w[3], wh2, wh3, wh4);

    const int GB = 512;

    // L1 (1->8): edge-parallel + node finish (writes bufB f32 + xhA f16)
    l1_edge<<<GB, 512, 0, stream>>>(records, bufA, w[0], iperm, y, epad);
    node_reduce<1, 8><<<cdiv(N * 4, B), B, 0, stream>>>(rowptr, yu, bufA,
                                                        root[0], bias[0], bufB, xhA, N);
    // L2 (8->16), MFMA
    edge_gemm_mfma<8, 16><<<GB, 512, 0, stream>>>(records, xhA, wh2, iperm, y, epad);
    node_reduce<8, 16><<<cdiv(N * 8, B), B, 0, stream>>>(rowptr, yu, bufB,
                                                         root[1], bias[1], bufA, xhB, N);
    // L3 (16->16), MFMA
    edge_gemm_mfma<16, 16><<<GB, 512, 0, stream>>>(records, xhB, wh3, iperm, y, epad);
    node_reduce<16, 16><<<cdiv(N * 8, B), B, 0, stream>>>(rowptr, yu, bufA,
                                                          root[2], bias[2], bufB, xhA, N);
    // L4 (16->8), MFMA with padded B
    edge_gemm_mfma<16, 8><<<GB, 512, 0, stream>>>(records, xhA, wh4, iperm, y, epad);
    node_reduce<16, 8><<<cdiv(N * 4, B), B, 0, stream>>>(rowptr, yu, bufB,
                                                         root[3], bias[3], bufA, xhB, N);
    // L5 (8->1): edge-parallel + scalar node finish
    l5_edge<<<GB, 512, 0, stream>>>(records, xhB, w[4], iperm, y5, epad);
    node_fin5<<<cdiv(N, B), B, 0, stream>>>(rowptr, y5, bufA, root[4], bias[4],
                                            (float*)d_out, N);
}

// Round 19
// 148.112 us; speedup vs baseline: 1.5298x; 1.0445x over previous
//
#include <hip/hip_runtime.h>
#include <math.h>

#define KSIZE 5
#define KTOT 125
#define CHUNK 2048

static constexpr float LOWER_CURV = -0.22703196f;
static constexpr float UPPER_CURV = 0.36853024f;

typedef _Float16 h2 __attribute__((ext_vector_type(2)));
typedef _Float16 h8_t __attribute__((ext_vector_type(8)));
typedef float f32x4 __attribute__((ext_vector_type(4)));

__device__ __forceinline__ unsigned pack_u32(float a, float b) {
    return __builtin_bit_cast(unsigned, __builtin_amdgcn_cvt_pkrtz(a, b));
}
__device__ __forceinline__ float fdot2f(h2 a, h2 b, float c) {
#if __has_builtin(__builtin_amdgcn_fdot2)
    return __builtin_amdgcn_fdot2(a, b, c, false);
#else
    return c + (float)a[0] * (float)b[0] + (float)a[1] * (float)b[1];
#endif
}

__host__ __device__ static inline int cdiv(int a, int b) { return (a + b - 1) / b; }

// basis from 10-bit quantized fractions; bb[t] matches TAP[t]
__device__ __forceinline__ void unpack_bb10(unsigned w1, float bb[8]) {
    const float s = 1.0f / 1023.0f;
    float f0 = (float)(w1 & 1023u) * s;
    float f1 = (float)((w1 >> 10) & 1023u) * s;
    float f2 = (float)((w1 >> 20) & 1023u) * s;
    float a0 = 1.f - f0, a1 = 1.f - f1, a2 = 1.f - f2;
    float p00 = a0 * a1, p10 = f0 * a1, p01 = a0 * f1, p11 = f0 * f1;
    bb[0] = p00 * a2; bb[1] = p10 * a2; bb[2] = p01 * a2; bb[3] = p11 * a2;
    bb[4] = p00 * f2; bb[5] = p10 * f2; bb[6] = p01 * f2; bb[7] = p11 * f2;
}

__device__ __forceinline__ void spline_wf(const float* __restrict__ a3,
                                          int& wib, float fr[3]) {
    int k[3];
#pragma unroll
    for (int d = 0; d < 3; ++d) {
        float p = fminf(fmaxf(a3[d], 0.f), 1.f) * 4.f;
        float f0 = fminf(floorf(p), 3.f);
        k[d] = (int)f0;
        fr[d] = p - f0;
    }
    wib = k[0] * 25 + k[1] * 5 + k[2];
}

// ---------- preamble kernels ----------

__global__ void zero_counts(int* __restrict__ p, int n) {
    int i = blockIdx.x * blockDim.x + threadIdx.x;
    if (i < n) p[i] = 0;
}

// x transform + dst histogram + block-aggregated wib histogram (counts/bcnt pre-zeroed)
__global__ __launch_bounds__(256) void hist_tr(
        const float* __restrict__ x, float* __restrict__ h,
        const int* __restrict__ dst, const float* __restrict__ attr,
        int* __restrict__ counts, int* __restrict__ bcnt, int N, int E) {
    __shared__ int lh[KTOT];
    const int tid = threadIdx.x;
    for (int i = tid; i < KTOT; i += 256) lh[i] = 0;
    __syncthreads();
    int i = blockIdx.x * 256 + tid;
    if (i < N) {
        float t = (x[i] - LOWER_CURV) / (UPPER_CURV - LOWER_CURV) * 20.0f - 10.0f;
        h[i] = fminf(fmaxf(t, -10.0f), 10.0f);
    }
    const int base = blockIdx.x * CHUNK;
#pragma unroll
    for (int k = 0; k < 8; ++k) {
        int e = base + tid + k * 256;
        if (e < E) {
            atomicAdd(&counts[dst[e]], 1);
            float a3[3] = {attr[e * 3], attr[e * 3 + 1], attr[e * 3 + 2]};
            int wib; float fr[3];
            spline_wf(a3, wib, fr);
            atomicAdd(&lh[wib], 1);
        }
    }
    __syncthreads();
    for (int j = tid; j < KTOT; j += 256) {
        int c = lh[j];
        if (c) atomicAdd(&bcnt[j], c);
    }
}

__global__ void scan_blocks(const int* __restrict__ counts, int* __restrict__ rowptr,
                            int* __restrict__ bsums, int n) {
    __shared__ int sh[256];
    int tid = threadIdx.x;
    int i = blockIdx.x * 256 + tid;
    int v = (i < n) ? counts[i] : 0;
    sh[tid] = v;
    __syncthreads();
    for (int off = 1; off < 256; off <<= 1) {
        int t = (tid >= off) ? sh[tid - off] : 0;
        __syncthreads();
        sh[tid] += t;
        __syncthreads();
    }
    if (i < n) rowptr[i] = sh[tid] - v;
    if (tid == 255) bsums[blockIdx.x] = sh[255];
}

// rowptr offset + cursor init; block 0 scans the 125 bucket counts PADDED TO 16
__global__ void add_offsets2(int* __restrict__ rowptr, const int* __restrict__ bsums,
                             int* __restrict__ cursor, const int* __restrict__ bcnt,
                             int* __restrict__ bases, int* __restrict__ bcursor,
                             int nb, int n, int E) {
    __shared__ int sh[256];
    __shared__ int sb[128];
    int tid = threadIdx.x;
    int v = (tid < nb) ? bsums[tid] : 0;
    sh[tid] = v;
    __syncthreads();
    for (int off = 1; off < 256; off <<= 1) {
        int t = (tid >= off) ? sh[tid - off] : 0;
        __syncthreads();
        sh[tid] += t;
        __syncthreads();
    }
    int boff = (blockIdx.x == 0) ? 0 : sh[blockIdx.x - 1];
    int i = blockIdx.x * 256 + tid;
    if (i < n) {
        int r = rowptr[i] + boff;
        rowptr[i] = r;
        cursor[i] = r;
    }
    if (i == 0) rowptr[n] = E;
    if (blockIdx.x == 0) {
        int cap = 0;
        if (tid < 128) {
            cap = (tid < KTOT) ? ((bcnt[tid] + 15) & ~15) : 0;
            sb[tid] = cap;
        }
        __syncthreads();
        for (int off = 1; off < 128; off <<= 1) {
            int t = (tid >= off && tid < 128) ? sb[tid - off] : 0;
            __syncthreads();
            if (tid < 128) sb[tid] += t;
            __syncthreads();
        }
        if (tid < KTOT) {
            int excl = sb[tid] - cap;
            bases[tid] = excl;
            bcursor[tid] = excl;
            if (tid == KTOT - 1) bases[KTOT] = excl + cap;
        }
    }
}

// GLOBAL bucket sort by wib (blocks < nchunk) — WITH FUSED L1 edge compute —
// + f16 weight-table prep (next nprep blocks; wh4 padded) + pad fill (last KTOT).
// Records 8B: w0 = src | wib<<18; w1 = q0|q1<<10|q2<<20.
__global__ __launch_bounds__(256) void scatter_prep(
        const int* __restrict__ src, const int* __restrict__ dst,
        const float* __restrict__ attr, int* __restrict__ cursor,
        int* __restrict__ bcursor, const int* __restrict__ bcnt,
        const int* __restrict__ bases,
        uint2* __restrict__ records, int* __restrict__ iperm,
        const float* __restrict__ h, const float* __restrict__ W1,
        _Float16* __restrict__ y1,
        int E, int nchunk, int nprep,
        const float* __restrict__ W2, const float* __restrict__ W3,
        const float* __restrict__ W4, _Float16* __restrict__ wh2,
        _Float16* __restrict__ wh3, _Float16* __restrict__ wh4) {
    __shared__ int lh[KTOT], lbase[KTOT], lrank[KTOT];
    __shared__ float Wl1[KTOT * 8];
    const int tid = threadIdx.x;

    if ((int)blockIdx.x >= nchunk + nprep) {
        // ---- pad fill ----
        int b = (int)blockIdx.x - nchunk - nprep;
        int s = bases[b] + bcnt[b];
        int e = bases[b + 1];
        for (int i = s + tid; i < e; i += 256) {
            records[i] = make_uint2((unsigned)b << 18, 0u);
            iperm[i] = E;                // dump row
        }
        return;
    }
    if ((int)blockIdx.x >= nchunk) {
        int idx = ((int)blockIdx.x - nchunk) * 256 + tid;   // < 80000
        if (idx >= 80000) return;
        if (idx < 16000) {
            int wi = idx / 128, q = idx % 128;
            int i = q / 16, o = q % 16;
            wh2[wi * 128 + o * 8 + i] = (_Float16)W2[idx];
        } else if (idx < 48000) {
            int r = idx - 16000;
            int wi = r / 256, q = r % 256;
            int i = q / 16, o = q % 16;
            wh3[wi * 256 + (i >> 3) * 128 + o * 8 + (i & 7)] = (_Float16)W3[r];
        } else {
            int r = idx - 48000;                 // < 32000
            int wi = r / 256, q = r % 256;
            int i = q / 16, o = q % 16;
            float val = (o < 8) ? W4[(wi * 16 + i) * 8 + o] : 0.0f;
            wh4[wi * 256 + (i >> 3) * 128 + o * 8 + (i & 7)] = (_Float16)val;
        }
        return;
    }

    for (int i = tid; i < KTOT; i += 256) { lh[i] = 0; lrank[i] = 0; }
    for (int i = tid; i < KTOT * 8; i += 256) Wl1[i] = W1[i];
    __syncthreads();
    const int base = blockIdx.x * CHUNK;

    int wibs[8]; unsigned w1s[8];
#pragma unroll
    for (int k = 0; k < 8; ++k) {
        int e = base + tid + k * 256;
        wibs[k] = -1;
        if (e < E) {
            float a3[3] = {attr[e * 3], attr[e * 3 + 1], attr[e * 3 + 2]};
            int wib; float fr[3];
            spline_wf(a3, wib, fr);
            wibs[k] = wib;
            unsigned q0 = (unsigned)__float2int_rn(fr[0] * 1023.f);
            unsigned q1 = (unsigned)__float2int_rn(fr[1] * 1023.f);
            unsigned q2 = (unsigned)__float2int_rn(fr[2] * 1023.f);
            w1s[k] = q0 | (q1 << 10) | (q2 << 20);
            atomicAdd(&lh[wib], 1);
        }
    }
    __syncthreads();
    for (int i = tid; i < KTOT; i += 256) {
        int c = lh[i];
        lbase[i] = c ? atomicAdd(&bcursor[i], c) : 0;
    }
    __syncthreads();
    constexpr int TAP[8] = {0, 25, 5, 30, 1, 26, 6, 31};
#pragma unroll
    for (int k = 0; k < 8; ++k) {
        int e = base + tid + k * 256;
        if (e < E) {
            int w = wibs[k];
            unsigned sn = (unsigned)src[e];
            int pos = lbase[w] + atomicAdd(&lrank[w], 1);
            records[pos] = make_uint2(sn | ((unsigned)w << 18), w1s[k]);
            int p = atomicAdd(&cursor[dst[e]], 1);
            iperm[pos] = p;
            // ---- fused L1: y1[p][0..7] = h[src] * sum_t bb_t W1[w+TAP[t]][:] ----
            float bb[8];
            unpack_bb10(w1s[k], bb);
            float xv = h[sn];
            float s[8];
#pragma unroll
            for (int o = 0; o < 8; ++o) s[o] = 0.f;
#pragma unroll
            for (int t = 0; t < 8; ++t) {
                const float* wp = &Wl1[(w + TAP[t]) * 8];
#pragma unroll
                for (int o = 0; o < 8; ++o) s[o] = fmaf(bb[t], wp[o], s[o]);
            }
            uint4 pk;
            pk.x = pack_u32(xv * s[0], xv * s[1]);
            pk.y = pack_u32(xv * s[2], xv * s[3]);
            pk.z = pack_u32(xv * s[4], xv * s[5]);
            pk.w = pack_u32(xv * s[6], xv * s[7]);
            *(uint4*)&y1[(size_t)p * 8] = pk;
        }
    }
}

// ---------- L5 edge kernel: lane=edge, f16 x, broadcast weights, scalar f32 y5 ----------
__global__ __launch_bounds__(512) void l5_edge(
        const uint2* __restrict__ records, const unsigned* __restrict__ xh,
        const float* __restrict__ W5,      // [125][8] f32
        const int* __restrict__ iperm, float* __restrict__ y5,
        const int* __restrict__ epad_ptr) {
    __shared__ h2 Wl[KTOT * 4];
    for (int i = threadIdx.x; i < KTOT * 4; i += 512)
        Wl[i] = __builtin_bit_cast(h2, pack_u32(W5[2 * i], W5[2 * i + 1]));
    __syncthreads();
    const int Ep = *epad_ptr;
    const int stride = gridDim.x * 512;
    constexpr int TAP[8] = {0, 25, 5, 30, 1, 26, 6, 31};
    for (int idx = blockIdx.x * 512 + threadIdx.x; idx < Ep; idx += stride) {
        uint2 rec = records[idx];
        float bb[8];
        unpack_bb10(rec.y, bb);
        const int wib = (int)(rec.x >> 18);
        uint4 xq = *(const uint4*)(xh + (size_t)(rec.x & 0x3FFFFu) * 4);
        h2 hx[4];
        hx[0] = __builtin_bit_cast(h2, xq.x);
        hx[1] = __builtin_bit_cast(h2, xq.y);
        hx[2] = __builtin_bit_cast(h2, xq.z);
        hx[3] = __builtin_bit_cast(h2, xq.w);
        float acc = 0.f;
#pragma unroll
        for (int t = 0; t < 8; ++t) {
            const h2* wp = &Wl[(wib + TAP[t]) * 4];
            float dot = 0.f;
            dot = fdot2f(hx[0], wp[0], dot);
            dot = fdot2f(hx[1], wp[1], dot);
            dot = fdot2f(hx[2], wp[2], dot);
            dot = fdot2f(hx[3], wp[3], dot);
            acc = fmaf(bb[t], dot, acc);
        }
        y5[iperm[idx]] = acc;
    }
}

// final node reduce for L5: sum scalars + root + bias + ELU
__global__ void node_fin5(const int* __restrict__ rowptr, const float* __restrict__ y5,
                          const float* __restrict__ x,   // [N][8] f32
                          const float* __restrict__ root, const float* __restrict__ bias,
                          float* __restrict__ out, int N) {
    int v = blockIdx.x * blockDim.x + threadIdx.x;
    if (v >= N) return;
    int beg = rowptr[v], end = rowptr[v + 1];
    float acc = bias[0];
    for (int p = beg; p < end; ++p) acc += y5[p];
#pragma unroll
    for (int i = 0; i < 8; ++i)
        acc = fmaf(x[(size_t)v * 8 + i], root[i], acc);
    out[v] = acc > 0.f ? acc : expm1f(acc);
}

// ---------- phase A (MFMA): 16-edge tiles, uniform wib ----------
template<int Cin, int CR>
__global__ __launch_bounds__(512) void edge_gemm_mfma(
        const uint2* __restrict__ records, const unsigned* __restrict__ xh,
        const _Float16* __restrict__ Wg, const int* __restrict__ iperm,
        _Float16* __restrict__ y, const int* __restrict__ epad_ptr) {
    constexpr int Cout = 16;
    constexpr int CC = Cin * Cout;
    constexpr int WH = KTOT * CC;
    constexpr int NM = Cin / 4;
    __shared__ __align__(16) _Float16 Wl[WH];
    for (int t = threadIdx.x; t < WH / 8; t += 512)
        ((uint4*)Wl)[t] = ((const uint4*)Wg)[t];
    __syncthreads();

    const int Ep = *epad_ptr;
    const int ntiles = Ep >> 4;
    const int lane = threadIdx.x & 63;
    const int o = lane & 15;
    const int kb = lane >> 4;
    const int chunk = (Cin == 16) ? (kb & 1) : 0;
    const int wid = blockIdx.x * 8 + (threadIdx.x >> 6);
    const int nwaves = gridDim.x * 8;
    constexpr int TAP[8] = {0, 25, 5, 30, 1, 26, 6, 31};

    for (int tile = wid; tile < ntiles; tile += nwaves) {
        const int tb = tile << 4;
        uint2 rec = records[tb + o];
        const int wib = (int)(((unsigned)__builtin_amdgcn_readfirstlane((int)rec.x)) >> 18);
        float bb[8];
        unpack_bb10(rec.y, bb);
        const unsigned sn = rec.x & 0x3FFFFu;
        uint4 xq = *(const uint4*)(xh + (size_t)sn * (Cin / 2) + chunk * 4);
        h2 xv[4];
        xv[0] = __builtin_bit_cast(h2, xq.x);
        xv[1] = __builtin_bit_cast(h2, xq.y);
        xv[2] = __builtin_bit_cast(h2, xq.z);
        xv[3] = __builtin_bit_cast(h2, xq.w);

        f32x4 acc = {0.f, 0.f, 0.f, 0.f};
#pragma unroll
        for (int m = 0; m < NM; ++m) {
            const int t = (Cin == 16) ? (2 * m + (kb >> 1)) : (4 * m + kb);
            const int wi = wib + TAP[t];
            _Float16 sh = (_Float16)bb[t];
            h2 ss; ss[0] = sh; ss[1] = sh;
            union { h8_t v; h2 h[4]; uint4 q; } A, B;
            A.h[0] = xv[0] * ss; A.h[1] = xv[1] * ss;
            A.h[2] = xv[2] * ss; A.h[3] = xv[3] * ss;
            B.q = *(const uint4*)&Wl[wi * CC + chunk * (8 * Cout) + o * 8];
            acc = __builtin_amdgcn_mfma_f32_16x16x32_f16(A.v, B.v, acc, 0, 0, 0);
        }
        if (CR == 16 || o < CR) {
#pragma unroll
            for (int r = 0; r < 4; ++r) {
                int dp = iperm[tb + kb * 4 + r];
                y[(size_t)dp * CR + o] = (_Float16)acc[r];
            }
        }
    }
}

// ---------- phase B: sequential y reduce + root + ELU; writes f32 + packed f16 ----------
template<int Cin, int Cout>
__global__ void node_reduce(const int* __restrict__ rowptr,
                            const unsigned* __restrict__ yu,
                            const float* __restrict__ x,
                            const float* __restrict__ root,
                            const float* __restrict__ bias,
                            float* __restrict__ out, unsigned* __restrict__ xh,
                            int N) {
    constexpr int C2 = Cout / 2;
    int t = blockIdx.x * blockDim.x + threadIdx.x;
    int v = t / C2, o2 = t % C2;
    if (v >= N) return;
    int beg = rowptr[v], end = rowptr[v + 1];
    float a0 = 0.f, a1 = 0.f;
    for (int p = beg; p < end; ++p) {
        h2 hh = __builtin_bit_cast(h2, yu[(size_t)p * C2 + o2]);
        a0 += (float)hh[0];
        a1 += (float)hh[1];
    }
    const int o = 2 * o2;
    a0 += bias[o]; a1 += bias[o + 1];
#pragma unroll
    for (int i = 0; i < Cin; ++i) {
        float xv = x[(size_t)v * Cin + i];
        a0 = fmaf(xv, root[i * Cout + o], a0);
        a1 = fmaf(xv, root[i * Cout + o + 1], a1);
    }
    a0 = a0 > 0.f ? a0 : expm1f(a0);
    a1 = a1 > 0.f ? a1 : expm1f(a1);
    ((float2*)out)[(size_t)v * C2 + o2] = make_float2(a0, a1);
    xh[(size_t)v * C2 + o2] = pack_u32(a0, a1);
}

// ---------- host ----------

static inline char* align256(char* p) {
    return (char*)(((uintptr_t)p + 255) & ~(uintptr_t)255);
}

extern "C" void kernel_launch(void* const* d_in, const int* in_sizes, int n_in,
                              void* d_out, int out_size, void* d_ws, size_t ws_size,
                              hipStream_t stream) {
    const float* x    = (const float*)d_in[0];
    const int*   ei   = (const int*)d_in[1];
    const float* attr = (const float*)d_in[2];
    const float* w[5]    = {(const float*)d_in[3],  (const float*)d_in[6],
                            (const float*)d_in[9],  (const float*)d_in[12],
                            (const float*)d_in[15]};
    const float* root[5] = {(const float*)d_in[4],  (const float*)d_in[7],
                            (const float*)d_in[10], (const float*)d_in[13],
                            (const float*)d_in[16]};
    const float* bias[5] = {(const float*)d_in[5],  (const float*)d_in[8],
                            (const float*)d_in[11], (const float*)d_in[14],
                            (const float*)d_in[17]};

    const int N = in_sizes[0];
    const int E = in_sizes[1] / 2;
    const int* src = ei;
    const int* dst = ei + E;
    const int EPCAP = E + 2048;

    char* ws = (char*)d_ws;
    float* bufA      = (float*)ws;    ws = align256(ws + (size_t)N * 16 * 4);
    float* bufB      = (float*)ws;    ws = align256(ws + (size_t)N * 16 * 4);
    int*   counts    = (int*)ws;      ws = align256(ws + (size_t)(N + 128) * 4);
    int*   bcnt      = counts + N;
    int*   cursor    = (int*)ws;      ws = align256(ws + (size_t)N * 4);
    int*   rowptr    = (int*)ws;      ws = align256(ws + (size_t)(N + 1) * 4);
    int*   bsums     = (int*)ws;      ws = align256(ws + 256 * 4);
    int*   bases     = (int*)ws;      ws = align256(ws + 128 * 4);
    int*   bcursor   = (int*)ws;      ws = align256(ws + 128 * 4);
    uint2* records   = (uint2*)ws;    ws = align256(ws + (size_t)EPCAP * 8);
    int*   iperm     = (int*)ws;      ws = align256(ws + (size_t)EPCAP * 4);
    _Float16* y      = (_Float16*)ws; ws = align256(ws + (size_t)(E + 16) * 16 * 2);
    unsigned* xhA    = (unsigned*)ws; ws = align256(ws + (size_t)N * 8 * 4);
    unsigned* xhB    = (unsigned*)ws; ws = align256(ws + (size_t)N * 8 * 4);
    _Float16* wh2    = (_Float16*)ws; ws = align256(ws + (size_t)KTOT * 8 * 16 * 2);
    _Float16* wh3    = (_Float16*)ws; ws = align256(ws + (size_t)KTOT * 16 * 16 * 2);
    _Float16* wh4    = (_Float16*)ws; ws = align256(ws + (size_t)KTOT * 16 * 16 * 2);

    const int B = 256;
    const int nb = cdiv(N, 256);
    const int nchunk = cdiv(E, CHUNK);
    const int nprep = cdiv(80000, 256);
    const int* epad = bases + KTOT;
    const unsigned* yu = (const unsigned*)y;
    float* y5 = (float*)y;

    zero_counts<<<cdiv(N + 128, B), B, 0, stream>>>(counts, N + 128);
    hist_tr<<<nchunk, 256, 0, stream>>>(x, bufA, dst, attr, counts, bcnt, N, E);
    scan_blocks<<<nb, 256, 0, stream>>>(counts, rowptr, bsums, N);
    add_offsets2<<<nb, 256, 0, stream>>>(rowptr, bsums, cursor, bcnt, bases,
                                         bcursor, nb, N, E);
    // bucket sort + weight prep + pad fill + FUSED L1 edge compute
    scatter_prep<<<nchunk + nprep + KTOT, 256, 0, stream>>>(
        src, dst, attr, cursor, bcursor, bcnt, bases,
        records, iperm, bufA, w[0], y,
        E, nchunk, nprep,
        w[1], w[2], w[3], wh2, wh3, wh4);

    const int GB = 512;

    // L1 node finish (y1 produced by scatter_prep); writes bufB f32 + xhA f16
    node_reduce<1, 8><<<cdiv(N * 4, B), B, 0, stream>>>(rowptr, yu, bufA,
                                                        root[0], bias[0], bufB, xhA, N);
    // L2 (8->16), MFMA
    edge_gemm_mfma<8, 16><<<GB, 512, 0, stream>>>(records, xhA, wh2, iperm, y, epad);
    node_reduce<8, 16><<<cdiv(N * 8, B), B, 0, stream>>>(rowptr, yu, bufB,
                                                         root[1], bias[1], bufA, xhB, N);
    // L3 (16->16), MFMA
    edge_gemm_mfma<16, 16><<<GB, 512, 0, stream>>>(records, xhB, wh3, iperm, y, epad);
    node_reduce<16, 16><<<cdiv(N * 8, B), B, 0, stream>>>(rowptr, yu, bufA,
                                                          root[2], bias[2], bufB, xhA, N);
    // L4 (16->8), MFMA with padded B
    edge_gemm_mfma<16, 8><<<GB, 512, 0, stream>>>(records, xhA, wh4, iperm, y, epad);
    node_reduce<16, 8><<<cdiv(N * 4, B), B, 0, stream>>>(rowptr, yu, bufB,
                                                         root[3], bias[3], bufA, xhB, N);
    // L5 (8->1): edge-parallel + scalar node finish
    l5_edge<<<GB, 512, 0, stream>>>(records, xhB, w[4], iperm, y5, epad);
    node_fin5<<<cdiv(N, B), B, 0, stream>>>(rowptr, y5, bufA, root[4], bias[4],
                                            (float*)d_out, N);
}